// Round 1
// baseline (264.180 us; speedup 1.0000x reference)
//
#include <hip/hip_runtime.h>
#include <hip/hip_bf16.h>

#define NQ 4096
#define NKV 4096
#define DIN 1024
#define NH 8
#define HD 64
#define DMODEL 512

typedef __attribute__((ext_vector_type(4))) float f32x4;
typedef __attribute__((ext_vector_type(8))) short short8;

#define GPTR(p) ((const __attribute__((address_space(1))) void*)(p))
#define SPTR(p) ((__attribute__((address_space(3))) void*)(p))
// XOR swizzle (in 8-element groups) to spread 128B-row LDS tiles across banks
#define SWZ(r) ((((r) ^ ((r) >> 3)) & 7) << 3)

__device__ __forceinline__ ushort f2b(float f) {
  // round-to-nearest-even f32 -> bf16 bits
  uint u = __float_as_uint(f);
  u = (u + 0x7fffu + ((u >> 16) & 1u)) >> 16;
  return (ushort)u;
}

// ---------------- cast: 3 equal-size f32 arrays -> bf16 ----------------
__global__ void cast3_kernel(const float* __restrict__ s0, const float* __restrict__ s1,
                             const float* __restrict__ s2, ushort* __restrict__ d0,
                             ushort* __restrict__ d1, ushort* __restrict__ d2, int shift) {
  const int n4 = 1 << shift;
  const int total = 3 * n4;
  for (int u = blockIdx.x * blockDim.x + threadIdx.x; u < total;
       u += gridDim.x * blockDim.x) {
    const int a = u >> shift;
    const int off = u & (n4 - 1);
    const float4* src = (const float4*)(a == 0 ? s0 : a == 1 ? s1 : s2);
    ushort* dst = a == 0 ? d0 : a == 1 ? d1 : d2;
    float4 v = src[off];
    ushort4 o = make_ushort4(f2b(v.x), f2b(v.y), f2b(v.z), f2b(v.w));
    ((ushort4*)dst)[off] = o;
  }
}

// ---------------- projection GEMM: C[4096][512] = A[4096][1024] * W^T ----------------
// W given as [512][1024] (row = n, contraction contiguous) — B^T layout.
__global__ __launch_bounds__(256) void proj_gemm(
    const ushort* __restrict__ A0, const ushort* __restrict__ B0, ushort* __restrict__ C0,
    const ushort* __restrict__ A1, const ushort* __restrict__ B1, ushort* __restrict__ C1,
    const ushort* __restrict__ A2, const ushort* __restrict__ B2, ushort* __restrict__ C2) {
  const int z = blockIdx.z;
  const ushort* A = z == 0 ? A0 : z == 1 ? A1 : A2;
  const ushort* B = z == 0 ? B0 : z == 1 ? B1 : B2;
  ushort* C = z == 0 ? C0 : z == 1 ? C1 : C2;

  __shared__ ushort As[128 * 32];
  __shared__ ushort Bs[128 * 32];
  const int tid = threadIdx.x;
  const int w = tid >> 6, lane = tid & 63;
  const int wr = w >> 1, wc = w & 1;
  const int bm = blockIdx.x, bn = blockIdx.y;

  f32x4 acc[4][4];
#pragma unroll
  for (int m = 0; m < 4; ++m)
#pragma unroll
    for (int n = 0; n < 4; ++n) acc[m][n] = (f32x4){0.f, 0.f, 0.f, 0.f};

  const size_t abase = (size_t)(bm * 128) * DIN;
  const size_t bbase = (size_t)(bn * 128) * DIN;
  const int schunk = (lane & 3) * 8;   // 16B chunk within 32-elem row
  const int srow_in = lane >> 2;       // 0..15 row within slot

  const int frow_a = wr * 64 + (lane & 15);
  const int frow_b = wc * 64 + (lane & 15);
  const int fcol = (lane >> 4) * 8;

  for (int k0 = 0; k0 < DIN; k0 += 32) {
#pragma unroll
    for (int j = 0; j < 2; ++j) {
      const int slot = w * 2 + j;
      const int row = slot * 16 + srow_in;
      __builtin_amdgcn_global_load_lds(GPTR(A + abase + (size_t)row * DIN + k0 + schunk),
                                       SPTR(As + slot * 512), 16, 0, 0);
      __builtin_amdgcn_global_load_lds(GPTR(B + bbase + (size_t)row * DIN + k0 + schunk),
                                       SPTR(Bs + slot * 512), 16, 0, 0);
    }
    __syncthreads();
    short8 af[4], bfr[4];
#pragma unroll
    for (int m = 0; m < 4; ++m)
      af[m] = *(const short8*)(As + (frow_a + m * 16) * 32 + fcol);
#pragma unroll
    for (int n = 0; n < 4; ++n)
      bfr[n] = *(const short8*)(Bs + (frow_b + n * 16) * 32 + fcol);
#pragma unroll
    for (int m = 0; m < 4; ++m)
#pragma unroll
      for (int n = 0; n < 4; ++n)
        acc[m][n] = __builtin_amdgcn_mfma_f32_16x16x32_bf16(af[m], bfr[n], acc[m][n], 0, 0, 0);
    __syncthreads();
  }

  const int orow = bm * 128 + wr * 64 + (lane >> 4) * 4;
  const int ocol = bn * 128 + wc * 64 + (lane & 15);
#pragma unroll
  for (int m = 0; m < 4; ++m)
#pragma unroll
    for (int n = 0; n < 4; ++n)
#pragma unroll
      for (int r = 0; r < 4; ++r)
        C[(size_t)(orow + m * 16 + r) * DMODEL + ocol + n * 16] = f2b(acc[m][n][r]);
}

// ---------------- fused flash attention ----------------
// Block: 256 threads (4 waves), QBLK=64 (16 q-rows/wave), KVBLK=64.
// Q/K/V are bf16 [4096][512]; head h occupies columns h*64..h*64+63.
__global__ __launch_bounds__(256) void attn_kernel(
    const ushort* __restrict__ Qp, const ushort* __restrict__ Kp,
    const ushort* __restrict__ Vp, float* __restrict__ out) {
  __shared__ ushort Qs[64 * 64];
  __shared__ ushort Ks[64 * 64];
  __shared__ ushort Vt[64 * 64];  // transposed V: [d][kv]
  __shared__ ushort Ps[64 * 64];  // P (bf16): [q][kv]
  const int h = blockIdx.y;
  const int q0 = blockIdx.x * 64;
  const int tid = threadIdx.x;
  const int w = tid >> 6, lane = tid & 63;
  const int l15 = lane & 15, l4 = lane >> 4;

  // stage Q once (pre-swizzled source so linear LDS write lands swizzled)
  {
    const int lrow = lane >> 3, lch = lane & 7;
#pragma unroll
    for (int j = 0; j < 2; ++j) {
      const int slot = w * 2 + j;
      const int row = slot * 8 + lrow;
      const int ch = (lch ^ ((row ^ (row >> 3)) & 7)) * 8;
      __builtin_amdgcn_global_load_lds(GPTR(Qp + (size_t)(q0 + row) * DMODEL + h * HD + ch),
                                       SPTR(Qs + slot * 512), 16, 0, 0);
    }
  }
  __syncthreads();
  // hoist Q fragments (constant across KV loop)
  short8 qa[2];
  {
    const int q = w * 16 + l15;
    const int sw = SWZ(q);
    qa[0] = *(const short8*)(Qs + q * 64 + ((8 * l4) ^ sw));
    qa[1] = *(const short8*)(Qs + q * 64 + ((32 + 8 * l4) ^ sw));
  }

  float m_run[4], l_run[4];
  f32x4 of[4];
#pragma unroll
  for (int r = 0; r < 4; ++r) { m_run[r] = -1e30f; l_run[r] = 0.f; }
#pragma unroll
  for (int fd = 0; fd < 4; ++fd) of[fd] = (f32x4){0.f, 0.f, 0.f, 0.f};

  for (int kv0 = 0; kv0 < NKV; kv0 += 64) {
    // stage K tile (pre-swizzled source)
    {
      const int lrow = lane >> 3, lch = lane & 7;
#pragma unroll
      for (int j = 0; j < 2; ++j) {
        const int slot = w * 2 + j;
        const int row = slot * 8 + lrow;
        const int ch = (lch ^ ((row ^ (row >> 3)) & 7)) * 8;
        __builtin_amdgcn_global_load_lds(GPTR(Kp + (size_t)(kv0 + row) * DMODEL + h * HD + ch),
                                         SPTR(Ks + slot * 512), 16, 0, 0);
      }
    }
    // stage V transposed: 2 rows/thread, pack pairs into b32 writes
    {
      const int pr = tid >> 3;        // 0..31 (kv pair)
      const int d0 = (tid & 7) * 8;
      const int kv = pr * 2;
      short8 v0 = *(const short8*)(Vp + (size_t)(kv0 + kv) * DMODEL + h * HD + d0);
      short8 v1 = *(const short8*)(Vp + (size_t)(kv0 + kv + 1) * DMODEL + h * HD + d0);
#pragma unroll
      for (int j = 0; j < 8; ++j) {
        const int d = d0 + j;
        const uint val = (uint)(ushort)v0[j] | ((uint)(ushort)v1[j] << 16);
        *(uint*)(Vt + d * 64 + (kv ^ SWZ(d))) = val;
      }
    }
    __syncthreads();

    // S = Q K^T for this wave's 16 q rows
    f32x4 sf[4];
#pragma unroll
    for (int fn = 0; fn < 4; ++fn) sf[fn] = (f32x4){0.f, 0.f, 0.f, 0.f};
#pragma unroll
    for (int fn = 0; fn < 4; ++fn) {
      const int kvr = fn * 16 + l15;
      const int sw = SWZ(kvr);
      short8 kb0 = *(const short8*)(Ks + kvr * 64 + ((8 * l4) ^ sw));
      short8 kb1 = *(const short8*)(Ks + kvr * 64 + ((32 + 8 * l4) ^ sw));
      sf[fn] = __builtin_amdgcn_mfma_f32_16x16x32_bf16(qa[0], kb0, sf[fn], 0, 0, 0);
      sf[fn] = __builtin_amdgcn_mfma_f32_16x16x32_bf16(qa[1], kb1, sf[fn], 0, 0, 0);
    }

    // online softmax (scale = 1/8)
    float ps[4][4];
    float rmax[4], rsum[4], alpha[4];
#pragma unroll
    for (int r = 0; r < 4; ++r)
      rmax[r] = 0.125f * fmaxf(fmaxf(sf[0][r], sf[1][r]), fmaxf(sf[2][r], sf[3][r]));
#pragma unroll
    for (int off = 1; off < 16; off <<= 1)
#pragma unroll
      for (int r = 0; r < 4; ++r) rmax[r] = fmaxf(rmax[r], __shfl_xor(rmax[r], off));
#pragma unroll
    for (int r = 0; r < 4; ++r) {
      const float mnew = fmaxf(m_run[r], rmax[r]);
      alpha[r] = __expf(m_run[r] - mnew);
      m_run[r] = mnew;
      rsum[r] = 0.f;
    }
#pragma unroll
    for (int fn = 0; fn < 4; ++fn)
#pragma unroll
      for (int r = 0; r < 4; ++r) {
        const float p = __expf(sf[fn][r] * 0.125f - m_run[r]);
        ps[fn][r] = p;
        rsum[r] += p;
      }
#pragma unroll
    for (int off = 1; off < 16; off <<= 1)
#pragma unroll
      for (int r = 0; r < 4; ++r) rsum[r] += __shfl_xor(rsum[r], off);
#pragma unroll
    for (int r = 0; r < 4; ++r) l_run[r] = l_run[r] * alpha[r] + rsum[r];
#pragma unroll
    for (int fd = 0; fd < 4; ++fd)
#pragma unroll
      for (int r = 0; r < 4; ++r) of[fd][r] *= alpha[r];

    // write P (bf16) to LDS — wave-local rows only
#pragma unroll
    for (int r = 0; r < 4; ++r) {
      const int q = w * 16 + l4 * 4 + r;
      const int sw = SWZ(q);
#pragma unroll
      for (int fn = 0; fn < 4; ++fn)
        Ps[q * 64 + ((fn * 16 + l15) ^ sw)] = f2b(ps[fn][r]);
    }
    asm volatile("s_waitcnt lgkmcnt(0)" ::: "memory");
    __builtin_amdgcn_sched_barrier(0);

    // O += P V
    {
      const int q = w * 16 + l15;
      const int swp = SWZ(q);
      short8 pa0 = *(const short8*)(Ps + q * 64 + ((8 * l4) ^ swp));
      short8 pa1 = *(const short8*)(Ps + q * 64 + ((32 + 8 * l4) ^ swp));
#pragma unroll
      for (int fd = 0; fd < 4; ++fd) {
        const int dr = fd * 16 + l15;
        const int sw = SWZ(dr);
        short8 vb0 = *(const short8*)(Vt + dr * 64 + ((8 * l4) ^ sw));
        short8 vb1 = *(const short8*)(Vt + dr * 64 + ((32 + 8 * l4) ^ sw));
        of[fd] = __builtin_amdgcn_mfma_f32_16x16x32_bf16(pa0, vb0, of[fd], 0, 0, 0);
        of[fd] = __builtin_amdgcn_mfma_f32_16x16x32_bf16(pa1, vb1, of[fd], 0, 0, 0);
      }
    }
    __syncthreads();
  }

  // epilogue: normalize and store f32
#pragma unroll
  for (int r = 0; r < 4; ++r) {
    const float inv = 1.0f / l_run[r];
    const int qrow = q0 + w * 16 + l4 * 4 + r;
#pragma unroll
    for (int fd = 0; fd < 4; ++fd)
      out[(size_t)qrow * DMODEL + h * HD + fd * 16 + l15] = of[fd][r] * inv;
  }
}

extern "C" void kernel_launch(void* const* d_in, const int* in_sizes, int n_in,
                              void* d_out, int out_size, void* d_ws, size_t ws_size,
                              hipStream_t stream) {
  const float* qin = (const float*)d_in[0];
  const float* kin = (const float*)d_in[1];
  const float* vin = (const float*)d_in[2];
  const float* Wq = (const float*)d_in[3];
  const float* Wk = (const float*)d_in[4];
  const float* Wv = (const float*)d_in[5];
  float* out = (float*)d_out;

  char* ws = (char*)d_ws;
  size_t off = 0;
  ushort* qb = (ushort*)(ws + off); off += (size_t)NQ * DIN * 2;
  ushort* kb = (ushort*)(ws + off); off += (size_t)NKV * DIN * 2;
  ushort* vb = (ushort*)(ws + off); off += (size_t)NKV * DIN * 2;
  ushort* wqb = (ushort*)(ws + off); off += (size_t)DMODEL * DIN * 2;
  ushort* wkb = (ushort*)(ws + off); off += (size_t)DMODEL * DIN * 2;
  ushort* wvb = (ushort*)(ws + off); off += (size_t)DMODEL * DIN * 2;
  ushort* Qp = (ushort*)(ws + off); off += (size_t)NQ * DMODEL * 2;
  ushort* Kp = (ushort*)(ws + off); off += (size_t)NKV * DMODEL * 2;
  ushort* Vp = (ushort*)(ws + off); off += (size_t)NKV * DMODEL * 2;

  // cast inputs (3 x 4096x1024, n4 = 2^20) and weights (3 x 512x1024, n4 = 2^17)
  cast3_kernel<<<2048, 256, 0, stream>>>(qin, kin, vin, qb, kb, vb, 20);
  cast3_kernel<<<1536, 256, 0, stream>>>(Wq, Wk, Wv, wqb, wkb, wvb, 17);
  // projections: Qp/Kp/Vp [4096][512] bf16
  proj_gemm<<<dim3(32, 4, 3), 256, 0, stream>>>(qb, wqb, Qp, kb, wkb, Kp, vb, wvb, Vp);
  // fused attention
  attn_kernel<<<dim3(64, NH), 256, 0, stream>>>(Qp, Kp, Vp, out);
}

// Round 2
// 262.769 us; speedup vs baseline: 1.0054x; 1.0054x over previous
//
#include <hip/hip_runtime.h>
#include <hip/hip_bf16.h>

#define NQ 4096
#define NKV 4096
#define DIN 1024
#define NH 8
#define HD 64
#define DMODEL 512
#define NSPLIT 2
#define KVHALF (NKV / NSPLIT)

typedef __attribute__((ext_vector_type(4))) float f32x4;
typedef __attribute__((ext_vector_type(8))) short short8;

#define GPTR(p) ((const __attribute__((address_space(1))) void*)(p))
#define SPTR(p) ((__attribute__((address_space(3))) void*)(p))
// XOR swizzle (in 8-element groups) to spread 128B-row LDS tiles across banks
#define SWZ(r) ((((r) ^ ((r) >> 3)) & 7) << 3)

__device__ __forceinline__ ushort f2b(float f) {
  // round-to-nearest-even f32 -> bf16 bits
  uint u = __float_as_uint(f);
  u = (u + 0x7fffu + ((u >> 16) & 1u)) >> 16;
  return (ushort)u;
}

// ---------------- cast: 3 equal-size f32 arrays -> bf16 ----------------
__global__ void cast3_kernel(const float* __restrict__ s0, const float* __restrict__ s1,
                             const float* __restrict__ s2, ushort* __restrict__ d0,
                             ushort* __restrict__ d1, ushort* __restrict__ d2, int shift) {
  const int n4 = 1 << shift;
  const int total = 3 * n4;
  for (int u = blockIdx.x * blockDim.x + threadIdx.x; u < total;
       u += gridDim.x * blockDim.x) {
    const int a = u >> shift;
    const int off = u & (n4 - 1);
    const float4* src = (const float4*)(a == 0 ? s0 : a == 1 ? s1 : s2);
    ushort* dst = a == 0 ? d0 : a == 1 ? d1 : d2;
    float4 v = src[off];
    ushort4 o = make_ushort4(f2b(v.x), f2b(v.y), f2b(v.z), f2b(v.w));
    ((ushort4*)dst)[off] = o;
  }
}

// ---------------- projection GEMM: C[4096][512] = A[4096][1024] * W^T ----------------
// 64x128 tile, 4 waves (2x2), grid 64 x 4 x 3 = 768 blocks -> 3 blocks/CU.
__global__ __launch_bounds__(256) void proj_gemm(
    const ushort* __restrict__ A0, const ushort* __restrict__ B0, ushort* __restrict__ C0,
    const ushort* __restrict__ A1, const ushort* __restrict__ B1, ushort* __restrict__ C1,
    const ushort* __restrict__ A2, const ushort* __restrict__ B2, ushort* __restrict__ C2) {
  const int z = blockIdx.z;
  const ushort* A = z == 0 ? A0 : z == 1 ? A1 : A2;
  const ushort* B = z == 0 ? B0 : z == 1 ? B1 : B2;
  ushort* C = z == 0 ? C0 : z == 1 ? C1 : C2;

  __shared__ ushort As[64 * 32];
  __shared__ ushort Bs[128 * 32];
  const int tid = threadIdx.x;
  const int w = tid >> 6, lane = tid & 63;
  const int wr = w >> 1, wc = w & 1;
  const int bm = blockIdx.x, bn = blockIdx.y;
  const int l15 = lane & 15, l4 = lane >> 4;

  f32x4 acc[2][4];
#pragma unroll
  for (int m = 0; m < 2; ++m)
#pragma unroll
    for (int n = 0; n < 4; ++n) acc[m][n] = (f32x4){0.f, 0.f, 0.f, 0.f};

  const size_t abase = (size_t)(bm * 64) * DIN;
  const size_t bbase = (size_t)(bn * 128) * DIN;
  const int srow = lane >> 2;          // 0..15 row within 16-row slot
  const int schunk = (lane & 3) * 8;   // 16B chunk within 32-elem row

  const int fcol = l4 * 8;

  for (int k0 = 0; k0 < DIN; k0 += 32) {
    // A: 64 rows, wave w stages rows w*16..w*16+15 (1 load/thread)
    __builtin_amdgcn_global_load_lds(
        GPTR(A + abase + (size_t)(w * 16 + srow) * DIN + k0 + schunk),
        SPTR(As + w * 512), 16, 0, 0);
    // B: 128 rows, 2 loads/thread
#pragma unroll
    for (int j = 0; j < 2; ++j) {
      const int slot = w * 2 + j;
      __builtin_amdgcn_global_load_lds(
          GPTR(B + bbase + (size_t)(slot * 16 + srow) * DIN + k0 + schunk),
          SPTR(Bs + slot * 512), 16, 0, 0);
    }
    __syncthreads();
    short8 af[2], bfr[4];
#pragma unroll
    for (int m = 0; m < 2; ++m)
      af[m] = *(const short8*)(As + (wr * 32 + m * 16 + l15) * 32 + fcol);
#pragma unroll
    for (int n = 0; n < 4; ++n)
      bfr[n] = *(const short8*)(Bs + (wc * 64 + n * 16 + l15) * 32 + fcol);
#pragma unroll
    for (int m = 0; m < 2; ++m)
#pragma unroll
      for (int n = 0; n < 4; ++n)
        acc[m][n] = __builtin_amdgcn_mfma_f32_16x16x32_bf16(af[m], bfr[n], acc[m][n], 0, 0, 0);
    __syncthreads();
  }

  const int orow = bm * 64 + wr * 32 + l4 * 4;
  const int ocol = bn * 128 + wc * 64 + l15;
#pragma unroll
  for (int m = 0; m < 2; ++m)
#pragma unroll
    for (int n = 0; n < 4; ++n)
#pragma unroll
      for (int r = 0; r < 4; ++r)
        C[(size_t)(orow + m * 16 + r) * DMODEL + ocol + n * 16] = f2b(acc[m][n][r]);
}

// ---------------- fused flash attention (KV-split x2, partial outputs) ----------------
// Block: 256 threads (4 waves), QBLK=64 (16 q-rows/wave), KVBLK=64, 32 iters/block.
// Single barrier per iteration; K double-buffered via global_load_lds, V via reg-staging.
__global__ __launch_bounds__(256) void attn_kernel(
    const ushort* __restrict__ Qp, const ushort* __restrict__ Kp,
    const ushort* __restrict__ Vp, float* __restrict__ Opart,
    float* __restrict__ Mpart, float* __restrict__ Lpart) {
  __shared__ ushort Ks[2][64 * 64];
  __shared__ ushort Vt[2][64 * 64];  // transposed V: [d][kv]
  __shared__ ushort Ps[64 * 64];     // Q staging (prologue), then P (bf16) [q][kv]
  const int h = blockIdx.y;
  const int q0 = blockIdx.x * 64;
  const int split = blockIdx.z;
  const int kvbase = split * KVHALF;
  const int tid = threadIdx.x;
  const int w = tid >> 6, lane = tid & 63;
  const int l15 = lane & 15, l4 = lane >> 4;

  // staging geometry: wave w stages rows w*16..w*16+15 (2 gload_lds/thread),
  // source pre-swizzled so linear LDS dest lands in swizzled layout (rule #21)
  const int lrow = lane >> 3, lch = lane & 7;
  int srow[2], sch[2];
#pragma unroll
  for (int j = 0; j < 2; ++j) {
    const int row = (w * 2 + j) * 8 + lrow;
    srow[j] = row;
    sch[j] = (lch ^ ((row ^ (row >> 3)) & 7)) * 8;
  }
  // V staging geometry: thread handles kv pair (2 rows) x 8 d-cols
  const int vkv = (tid >> 3) * 2;
  const int vd0 = (tid & 7) * 8;

  // ---- prologue: stage Q (into Ps), K(0), V(0) ----
#pragma unroll
  for (int j = 0; j < 2; ++j)
    __builtin_amdgcn_global_load_lds(
        GPTR(Qp + (size_t)(q0 + srow[j]) * DMODEL + h * HD + sch[j]),
        SPTR(Ps + (w * 2 + j) * 512), 16, 0, 0);
#pragma unroll
  for (int j = 0; j < 2; ++j)
    __builtin_amdgcn_global_load_lds(
        GPTR(Kp + (size_t)(kvbase + srow[j]) * DMODEL + h * HD + sch[j]),
        SPTR(Ks[0] + (w * 2 + j) * 512), 16, 0, 0);
  short8 vr0 = *(const short8*)(Vp + (size_t)(kvbase + vkv) * DMODEL + h * HD + vd0);
  short8 vr1 = *(const short8*)(Vp + (size_t)(kvbase + vkv + 1) * DMODEL + h * HD + vd0);
  asm volatile("s_waitcnt vmcnt(0)" ::: "memory");
  // hoist Q fragments (wave-local rows; DS in-order per wave => safe to reuse Ps later)
  short8 qa0, qa1;
  {
    const int q = w * 16 + l15;
    const int sw = SWZ(q);
    qa0 = *(const short8*)(Ps + q * 64 + ((8 * l4) ^ sw));
    qa1 = *(const short8*)(Ps + q * 64 + ((32 + 8 * l4) ^ sw));
  }
  // write V tile 0 transposed
#pragma unroll
  for (int j = 0; j < 8; ++j) {
    const int d = vd0 + j;
    const uint val = (uint)(ushort)vr0[j] | ((uint)(ushort)vr1[j] << 16);
    *(uint*)(Vt[0] + d * 64 + (vkv ^ SWZ(d))) = val;
  }
  __syncthreads();

  float m_run[4], l_run[4];
  f32x4 of[4];
#pragma unroll
  for (int r = 0; r < 4; ++r) { m_run[r] = -1e30f; l_run[r] = 0.f; }
#pragma unroll
  for (int fd = 0; fd < 4; ++fd) of[fd] = (f32x4){0.f, 0.f, 0.f, 0.f};

  int cur = 0;
  for (int it = 0; it < KVHALF / 64; ++it) {
    // ---- issue next tile's loads first (hide latency under compute) ----
    short8 pv0, pv1;
    const bool pf = (it + 1) < KVHALF / 64;
    if (pf) {
      const int kvn = kvbase + (it + 1) * 64;
#pragma unroll
      for (int j = 0; j < 2; ++j)
        __builtin_amdgcn_global_load_lds(
            GPTR(Kp + (size_t)(kvn + srow[j]) * DMODEL + h * HD + sch[j]),
            SPTR(Ks[cur ^ 1] + (w * 2 + j) * 512), 16, 0, 0);
      pv0 = *(const short8*)(Vp + (size_t)(kvn + vkv) * DMODEL + h * HD + vd0);
      pv1 = *(const short8*)(Vp + (size_t)(kvn + vkv + 1) * DMODEL + h * HD + vd0);
    }

    // ---- S = Q K^T for this wave's 16 q rows ----
    f32x4 sf[4];
#pragma unroll
    for (int fn = 0; fn < 4; ++fn) sf[fn] = (f32x4){0.f, 0.f, 0.f, 0.f};
#pragma unroll
    for (int fn = 0; fn < 4; ++fn) {
      const int kvr = fn * 16 + l15;
      const int sw = SWZ(kvr);
      short8 kb0 = *(const short8*)(Ks[cur] + kvr * 64 + ((8 * l4) ^ sw));
      short8 kb1 = *(const short8*)(Ks[cur] + kvr * 64 + ((32 + 8 * l4) ^ sw));
      sf[fn] = __builtin_amdgcn_mfma_f32_16x16x32_bf16(qa0, kb0, sf[fn], 0, 0, 0);
      sf[fn] = __builtin_amdgcn_mfma_f32_16x16x32_bf16(qa1, kb1, sf[fn], 0, 0, 0);
    }

    // ---- online softmax (scale = 1/8) ----
    float ps[4][4];
    float rmax[4], rsum[4], alpha[4];
#pragma unroll
    for (int r = 0; r < 4; ++r)
      rmax[r] = 0.125f * fmaxf(fmaxf(sf[0][r], sf[1][r]), fmaxf(sf[2][r], sf[3][r]));
#pragma unroll
    for (int off = 1; off < 16; off <<= 1)
#pragma unroll
      for (int r = 0; r < 4; ++r) rmax[r] = fmaxf(rmax[r], __shfl_xor(rmax[r], off));
#pragma unroll
    for (int r = 0; r < 4; ++r) {
      const float mnew = fmaxf(m_run[r], rmax[r]);
      alpha[r] = __expf(m_run[r] - mnew);
      m_run[r] = mnew;
      rsum[r] = 0.f;
    }
#pragma unroll
    for (int fn = 0; fn < 4; ++fn)
#pragma unroll
      for (int r = 0; r < 4; ++r) {
        const float p = __expf(sf[fn][r] * 0.125f - m_run[r]);
        ps[fn][r] = p;
        rsum[r] += p;
      }
#pragma unroll
    for (int off = 1; off < 16; off <<= 1)
#pragma unroll
      for (int r = 0; r < 4; ++r) rsum[r] += __shfl_xor(rsum[r], off);
#pragma unroll
    for (int r = 0; r < 4; ++r) l_run[r] = l_run[r] * alpha[r] + rsum[r];
#pragma unroll
    for (int fd = 0; fd < 4; ++fd)
#pragma unroll
      for (int r = 0; r < 4; ++r) of[fd][r] *= alpha[r];

    // ---- write P (bf16) to LDS — wave-local rows only ----
#pragma unroll
    for (int r = 0; r < 4; ++r) {
      const int q = w * 16 + l4 * 4 + r;
      const int sw = SWZ(q);
#pragma unroll
      for (int fn = 0; fn < 4; ++fn)
        Ps[q * 64 + ((fn * 16 + l15) ^ sw)] = f2b(ps[fn][r]);
    }
    asm volatile("s_waitcnt lgkmcnt(0)" ::: "memory");
    __builtin_amdgcn_sched_barrier(0);

    // ---- O += P V ----
    {
      const int q = w * 16 + l15;
      const int swp = SWZ(q);
      short8 pa0 = *(const short8*)(Ps + q * 64 + ((8 * l4) ^ swp));
      short8 pa1 = *(const short8*)(Ps + q * 64 + ((32 + 8 * l4) ^ swp));
#pragma unroll
      for (int fd = 0; fd < 4; ++fd) {
        const int dr = fd * 16 + l15;
        const int sw = SWZ(dr);
        short8 vb0 = *(const short8*)(Vt[cur] + dr * 64 + ((8 * l4) ^ sw));
        short8 vb1 = *(const short8*)(Vt[cur] + dr * 64 + ((32 + 8 * l4) ^ sw));
        of[fd] = __builtin_amdgcn_mfma_f32_16x16x32_bf16(pa0, vb0, of[fd], 0, 0, 0);
        of[fd] = __builtin_amdgcn_mfma_f32_16x16x32_bf16(pa1, vb1, of[fd], 0, 0, 0);
      }
    }

    // ---- land next V tile (compiler inserts vmcnt wait on pv regs) ----
    if (pf) {
#pragma unroll
      for (int j = 0; j < 8; ++j) {
        const int d = vd0 + j;
        const uint val = (uint)(ushort)pv0[j] | ((uint)(ushort)pv1[j] << 16);
        *(uint*)(Vt[cur ^ 1] + d * 64 + (vkv ^ SWZ(d))) = val;
      }
    }
    __syncthreads();  // implicit vmcnt(0)+lgkmcnt(0) drain covers K(t+1) visibility
    cur ^= 1;
  }

  // ---- epilogue: store UNNORMALIZED partial O and per-row m,l ----
#pragma unroll
  for (int r = 0; r < 4; ++r) {
    const int qrow = q0 + w * 16 + l4 * 4 + r;
#pragma unroll
    for (int fd = 0; fd < 4; ++fd)
      Opart[(size_t)split * (NQ * DMODEL) + (size_t)qrow * DMODEL + h * HD + fd * 16 + l15] =
          of[fd][r];
  }
  if (l15 == 0) {
#pragma unroll
    for (int r = 0; r < 4; ++r) {
      const int qrow = q0 + w * 16 + l4 * 4 + r;
      Mpart[(split * NH + h) * NQ + qrow] = m_run[r];
      Lpart[(split * NH + h) * NQ + qrow] = l_run[r];
    }
  }
}

// ---------------- merge the 2 KV-split partials ----------------
__global__ __launch_bounds__(256) void merge_kernel(
    const float* __restrict__ Opart, const float* __restrict__ Mpart,
    const float* __restrict__ Lpart, float* __restrict__ out) {
  const int i4 = blockIdx.x * 256 + threadIdx.x;  // group of 4 floats
  const int i = i4 * 4;
  const int q = i >> 9;        // / DMODEL
  const int col = i & 511;
  const int h = col >> 6;
  const float m0 = Mpart[h * NQ + q];
  const float m1 = Mpart[NH * NQ + h * NQ + q];
  const float mm = fmaxf(m0, m1);
  const float w0 = __expf(m0 - mm);
  const float w1 = __expf(m1 - mm);
  const float l = w0 * Lpart[h * NQ + q] + w1 * Lpart[NH * NQ + h * NQ + q];
  const float inv = 1.0f / l;
  const float4 o0 = ((const float4*)Opart)[i4];
  const float4 o1 = ((const float4*)(Opart + (size_t)NQ * DMODEL))[i4];
  float4 o;
  o.x = (w0 * o0.x + w1 * o1.x) * inv;
  o.y = (w0 * o0.y + w1 * o1.y) * inv;
  o.z = (w0 * o0.z + w1 * o1.z) * inv;
  o.w = (w0 * o0.w + w1 * o1.w) * inv;
  ((float4*)out)[i4] = o;
}

extern "C" void kernel_launch(void* const* d_in, const int* in_sizes, int n_in,
                              void* d_out, int out_size, void* d_ws, size_t ws_size,
                              hipStream_t stream) {
  const float* qin = (const float*)d_in[0];
  const float* kin = (const float*)d_in[1];
  const float* vin = (const float*)d_in[2];
  const float* Wq = (const float*)d_in[3];
  const float* Wk = (const float*)d_in[4];
  const float* Wv = (const float*)d_in[5];
  float* out = (float*)d_out;

  char* ws = (char*)d_ws;
  size_t off = 0;
  ushort* qb = (ushort*)(ws + off); off += (size_t)NQ * DIN * 2;
  ushort* kb = (ushort*)(ws + off); off += (size_t)NKV * DIN * 2;
  ushort* vb = (ushort*)(ws + off); off += (size_t)NKV * DIN * 2;
  ushort* wqb = (ushort*)(ws + off); off += (size_t)DMODEL * DIN * 2;
  ushort* wkb = (ushort*)(ws + off); off += (size_t)DMODEL * DIN * 2;
  ushort* wvb = (ushort*)(ws + off); off += (size_t)DMODEL * DIN * 2;
  ushort* Qp = (ushort*)(ws + off); off += (size_t)NQ * DMODEL * 2;
  ushort* Kp = (ushort*)(ws + off); off += (size_t)NKV * DMODEL * 2;
  ushort* Vp = (ushort*)(ws + off); off += (size_t)NKV * DMODEL * 2;
  float* Opart = (float*)(ws + off); off += (size_t)NSPLIT * NQ * DMODEL * 4;
  float* Mpart = (float*)(ws + off); off += (size_t)NSPLIT * NH * NQ * 4;
  float* Lpart = (float*)(ws + off); off += (size_t)NSPLIT * NH * NQ * 4;

  // cast inputs (3 x 4096x1024, n4 = 2^20) and weights (3 x 512x1024, n4 = 2^17)
  cast3_kernel<<<2048, 256, 0, stream>>>(qin, kin, vin, qb, kb, vb, 20);
  cast3_kernel<<<1536, 256, 0, stream>>>(Wq, Wk, Wv, wqb, wkb, wvb, 17);
  // projections: Qp/Kp/Vp [4096][512] bf16
  proj_gemm<<<dim3(64, 4, 3), 256, 0, stream>>>(qb, wqb, Qp, kb, wkb, Kp, vb, wvb, Vp);
  // fused attention, KV-split x2
  attn_kernel<<<dim3(64, NH, NSPLIT), 256, 0, stream>>>(Qp, Kp, Vp, Opart, Mpart, Lpart);
  // merge partials
  merge_kernel<<<(NQ * DMODEL / 4) / 256, 256, 0, stream>>>(Opart, Mpart, Lpart, out);
}

// Round 3
// 226.363 us; speedup vs baseline: 1.1671x; 1.1608x over previous
//
#include <hip/hip_runtime.h>
#include <hip/hip_bf16.h>

#define NQ 4096
#define NKV 4096
#define DIN 1024
#define NH 8
#define HD 64
#define DMODEL 512
#define NSPLIT 2
#define KVHALF (NKV / NSPLIT)

typedef __attribute__((ext_vector_type(4))) float f32x4;
typedef __attribute__((ext_vector_type(8))) short short8;

#define GPTR(p) ((const __attribute__((address_space(1))) void*)(p))
#define SPTR(p) ((__attribute__((address_space(3))) void*)(p))
// XOR swizzle (in 8-element groups) to spread 128B-row LDS tiles across banks
#define SWZ(r) ((((r) ^ ((r) >> 3)) & 7) << 3)

// 0.125 (1/sqrt(64)) * log2(e): softmax computed in exp2 domain
#define SM_SCALE 0.1803368801111204f

__device__ __forceinline__ ushort f2b(float f) {
  // round-to-nearest-even f32 -> bf16 bits
  uint u = __float_as_uint(f);
  u = (u + 0x7fffu + ((u >> 16) & 1u)) >> 16;
  return (ushort)u;
}

__device__ __forceinline__ uint cvt_pk_bf16(float lo, float hi) {
  uint r;
  asm("v_cvt_pk_bf16_f32 %0, %1, %2" : "=v"(r) : "v"(lo), "v"(hi));
  return r;
}

__device__ __forceinline__ float fast_exp2(float x) {
  float r;
  asm("v_exp_f32 %0, %1" : "=v"(r) : "v"(x));
  return r;
}

// ---------------- cast: 3 equal-size f32 arrays -> bf16 ----------------
__global__ void cast3_kernel(const float* __restrict__ s0, const float* __restrict__ s1,
                             const float* __restrict__ s2, ushort* __restrict__ d0,
                             ushort* __restrict__ d1, ushort* __restrict__ d2, int shift) {
  const int n4 = 1 << shift;
  const int total = 3 * n4;
  for (int u = blockIdx.x * blockDim.x + threadIdx.x; u < total;
       u += gridDim.x * blockDim.x) {
    const int a = u >> shift;
    const int off = u & (n4 - 1);
    const float4* src = (const float4*)(a == 0 ? s0 : a == 1 ? s1 : s2);
    ushort* dst = a == 0 ? d0 : a == 1 ? d1 : d2;
    float4 v = src[off];
    ushort4 o = make_ushort4(f2b(v.x), f2b(v.y), f2b(v.z), f2b(v.w));
    ((ushort4*)dst)[off] = o;
  }
}

// ---------------- projection GEMM: C[4096][512] = A[4096][1024] * W^T ----------------
// 64x128 tile, 4 waves (2x2), grid 64 x 4 x 3 = 768 blocks -> 3 blocks/CU.
__global__ __launch_bounds__(256) void proj_gemm(
    const ushort* __restrict__ A0, const ushort* __restrict__ B0, ushort* __restrict__ C0,
    const ushort* __restrict__ A1, const ushort* __restrict__ B1, ushort* __restrict__ C1,
    const ushort* __restrict__ A2, const ushort* __restrict__ B2, ushort* __restrict__ C2) {
  const int z = blockIdx.z;
  const ushort* A = z == 0 ? A0 : z == 1 ? A1 : A2;
  const ushort* B = z == 0 ? B0 : z == 1 ? B1 : B2;
  ushort* C = z == 0 ? C0 : z == 1 ? C1 : C2;

  __shared__ ushort As[64 * 32];
  __shared__ ushort Bs[128 * 32];
  const int tid = threadIdx.x;
  const int w = tid >> 6, lane = tid & 63;
  const int wr = w >> 1, wc = w & 1;
  const int bm = blockIdx.x, bn = blockIdx.y;
  const int l15 = lane & 15, l4 = lane >> 4;

  f32x4 acc[2][4];
#pragma unroll
  for (int m = 0; m < 2; ++m)
#pragma unroll
    for (int n = 0; n < 4; ++n) acc[m][n] = (f32x4){0.f, 0.f, 0.f, 0.f};

  const size_t abase = (size_t)(bm * 64) * DIN;
  const size_t bbase = (size_t)(bn * 128) * DIN;
  const int srow = lane >> 2;          // 0..15 row within 16-row slot
  const int schunk = (lane & 3) * 8;   // 16B chunk within 32-elem row

  const int fcol = l4 * 8;

  for (int k0 = 0; k0 < DIN; k0 += 32) {
    // A: 64 rows, wave w stages rows w*16..w*16+15 (1 load/thread)
    __builtin_amdgcn_global_load_lds(
        GPTR(A + abase + (size_t)(w * 16 + srow) * DIN + k0 + schunk),
        SPTR(As + w * 512), 16, 0, 0);
    // B: 128 rows, 2 loads/thread
#pragma unroll
    for (int j = 0; j < 2; ++j) {
      const int slot = w * 2 + j;
      __builtin_amdgcn_global_load_lds(
          GPTR(B + bbase + (size_t)(slot * 16 + srow) * DIN + k0 + schunk),
          SPTR(Bs + slot * 512), 16, 0, 0);
    }
    __syncthreads();
    short8 af[2], bfr[4];
#pragma unroll
    for (int m = 0; m < 2; ++m)
      af[m] = *(const short8*)(As + (wr * 32 + m * 16 + l15) * 32 + fcol);
#pragma unroll
    for (int n = 0; n < 4; ++n)
      bfr[n] = *(const short8*)(Bs + (wc * 64 + n * 16 + l15) * 32 + fcol);
#pragma unroll
    for (int m = 0; m < 2; ++m)
#pragma unroll
      for (int n = 0; n < 4; ++n)
        acc[m][n] = __builtin_amdgcn_mfma_f32_16x16x32_bf16(af[m], bfr[n], acc[m][n], 0, 0, 0);
    __syncthreads();
  }

  const int orow = bm * 64 + wr * 32 + l4 * 4;
  const int ocol = bn * 128 + wc * 64 + l15;
#pragma unroll
  for (int m = 0; m < 2; ++m)
#pragma unroll
    for (int n = 0; n < 4; ++n)
#pragma unroll
      for (int r = 0; r < 4; ++r)
        C[(size_t)(orow + m * 16 + r) * DMODEL + ocol + n * 16] = f2b(acc[m][n][r]);
}

// ---------------- fused flash attention (KV-split x2, partial outputs) ----------------
// Block: 256 threads (4 waves), QBLK=64 (16 q-rows/wave), KVBLK=64, 32 iters/block.
// Swapped QK^T (mfma(K,Q)): each lane owns one q-row (q=lane&15) with 16 in-register
// kv values -> in-register softmax (2+2 shfl instead of 32), b64 P writes.
__global__ __launch_bounds__(256) void attn_kernel(
    const ushort* __restrict__ Qp, const ushort* __restrict__ Kp,
    const ushort* __restrict__ Vp, float* __restrict__ Opart,
    float* __restrict__ Mpart, float* __restrict__ Lpart) {
  __shared__ ushort Ks[2][64 * 64];
  __shared__ ushort Vt[2][64 * 64];  // transposed V: [d][kv]
  __shared__ ushort Ps[64 * 64];     // Q staging (prologue), then P (bf16) [q][kv]
  const int h = blockIdx.y;
  const int q0 = blockIdx.x * 64;
  const int split = blockIdx.z;
  const int kvbase = split * KVHALF;
  const int tid = threadIdx.x;
  const int w = tid >> 6, lane = tid & 63;
  const int l15 = lane & 15, l4 = lane >> 4;

  // staging geometry: wave w stages rows w*16..w*16+15 (2 gload_lds/thread),
  // source pre-swizzled so linear LDS dest lands in swizzled layout (rule #21)
  const int lrow = lane >> 3, lch = lane & 7;
  int srow[2], sch[2];
#pragma unroll
  for (int j = 0; j < 2; ++j) {
    const int row = (w * 2 + j) * 8 + lrow;
    srow[j] = row;
    sch[j] = (lch ^ ((row ^ (row >> 3)) & 7)) * 8;
  }
  // V staging geometry: kv from LOW tid bits, d-octet from high bits
  // (bank-conflict-free: bank = (kv&6)/2 + 4*(s_d ^ hi(kv)) spreads 2 lanes/bank)
  const int vkv = w * 16 + (lane & 7) * 2;
  const int vd0 = ((lane >> 3) & 7) * 8;

  // ---- prologue: stage Q (into Ps), K(0), V(0) ----
#pragma unroll
  for (int j = 0; j < 2; ++j)
    __builtin_amdgcn_global_load_lds(
        GPTR(Qp + (size_t)(q0 + srow[j]) * DMODEL + h * HD + sch[j]),
        SPTR(Ps + (w * 2 + j) * 512), 16, 0, 0);
#pragma unroll
  for (int j = 0; j < 2; ++j)
    __builtin_amdgcn_global_load_lds(
        GPTR(Kp + (size_t)(kvbase + srow[j]) * DMODEL + h * HD + sch[j]),
        SPTR(Ks[0] + (w * 2 + j) * 512), 16, 0, 0);
  short8 vr0 = *(const short8*)(Vp + (size_t)(kvbase + vkv) * DMODEL + h * HD + vd0);
  short8 vr1 = *(const short8*)(Vp + (size_t)(kvbase + vkv + 1) * DMODEL + h * HD + vd0);
  asm volatile("s_waitcnt vmcnt(0)" ::: "memory");
  // hoist Q fragments (wave staged its own rows; reads are wave-local)
  short8 qa0, qa1;
  {
    const int q = w * 16 + l15;
    const int sw = SWZ(q);
    qa0 = *(const short8*)(Ps + q * 64 + ((8 * l4) ^ sw));
    qa1 = *(const short8*)(Ps + q * 64 + ((32 + 8 * l4) ^ sw));
  }
  // write V tile 0 transposed
#pragma unroll
  for (int j = 0; j < 8; ++j) {
    const int d = vd0 + j;
    const uint val = (uint)(ushort)vr0[j] | ((uint)(ushort)vr1[j] << 16);
    *(uint*)(Vt[0] + d * 64 + (vkv ^ SWZ(d))) = val;
  }
  __syncthreads();

  // per-lane softmax state for q-row (w*16 + l15); replicated across the 4 lane-groups
  float m_run = -1e30f, l_run = 0.f;
  f32x4 of[4];
#pragma unroll
  for (int fd = 0; fd < 4; ++fd) of[fd] = (f32x4){0.f, 0.f, 0.f, 0.f};

  int cur = 0;
  for (int it = 0; it < KVHALF / 64; ++it) {
    // ---- issue next tile's loads first (hide latency under compute) ----
    short8 pv0, pv1;
    const bool pf = (it + 1) < KVHALF / 64;
    if (pf) {
      const int kvn = kvbase + (it + 1) * 64;
#pragma unroll
      for (int j = 0; j < 2; ++j)
        __builtin_amdgcn_global_load_lds(
            GPTR(Kp + (size_t)(kvn + srow[j]) * DMODEL + h * HD + sch[j]),
            SPTR(Ks[cur ^ 1] + (w * 2 + j) * 512), 16, 0, 0);
      pv0 = *(const short8*)(Vp + (size_t)(kvn + vkv) * DMODEL + h * HD + vd0);
      pv1 = *(const short8*)(Vp + (size_t)(kvn + vkv + 1) * DMODEL + h * HD + vd0);
    }

    // ---- S^T = K Q^T : lane holds S[kv = fn*16 + l4*4 + r][q = l15] ----
    f32x4 sf[4];
#pragma unroll
    for (int fn = 0; fn < 4; ++fn) sf[fn] = (f32x4){0.f, 0.f, 0.f, 0.f};
#pragma unroll
    for (int fn = 0; fn < 4; ++fn) {
      const int kvr = fn * 16 + l15;
      const int sw = SWZ(kvr);
      short8 kb0 = *(const short8*)(Ks[cur] + kvr * 64 + ((8 * l4) ^ sw));
      short8 kb1 = *(const short8*)(Ks[cur] + kvr * 64 + ((32 + 8 * l4) ^ sw));
      sf[fn] = __builtin_amdgcn_mfma_f32_16x16x32_bf16(kb0, qa0, sf[fn], 0, 0, 0);
      sf[fn] = __builtin_amdgcn_mfma_f32_16x16x32_bf16(kb1, qa1, sf[fn], 0, 0, 0);
    }

    // ---- in-register online softmax (exp2 domain) ----
    // local max over this lane's 16 kv values
    float t0 = fmaxf(fmaxf(sf[0][0], sf[0][1]), fmaxf(sf[0][2], sf[0][3]));
    float t1 = fmaxf(fmaxf(sf[1][0], sf[1][1]), fmaxf(sf[1][2], sf[1][3]));
    float t2 = fmaxf(fmaxf(sf[2][0], sf[2][1]), fmaxf(sf[2][2], sf[2][3]));
    float t3 = fmaxf(fmaxf(sf[3][0], sf[3][1]), fmaxf(sf[3][2], sf[3][3]));
    float rmax2 = fmaxf(fmaxf(t0, t1), fmaxf(t2, t3)) * SM_SCALE;
    // group reduce across the 4 lanes sharing this q-row
    rmax2 = fmaxf(rmax2, __shfl_xor(rmax2, 16));
    rmax2 = fmaxf(rmax2, __shfl_xor(rmax2, 32));
    // T13 defer-max: only rescale when max grows materially (bounds p by 2^8)
    if (__any(rmax2 > m_run + 8.0f)) {
      const float mnew = fmaxf(m_run, rmax2);
      const float alpha = fast_exp2(m_run - mnew);
      m_run = mnew;
      l_run *= alpha;
      float ar[4];
#pragma unroll
      for (int r = 0; r < 4; ++r) ar[r] = __shfl(alpha, l4 * 4 + r);
#pragma unroll
      for (int fd = 0; fd < 4; ++fd)
#pragma unroll
        for (int r = 0; r < 4; ++r) of[fd][r] *= ar[r];
    }
    float p[4][4];
    float rsum = 0.f;
#pragma unroll
    for (int fn = 0; fn < 4; ++fn)
#pragma unroll
      for (int r = 0; r < 4; ++r) {
        const float v = fast_exp2(__builtin_fmaf(sf[fn][r], SM_SCALE, -m_run));
        p[fn][r] = v;
        rsum += v;
      }
    rsum += __shfl_xor(rsum, 16);
    rsum += __shfl_xor(rsum, 32);
    l_run += rsum;

    // ---- pack P to bf16 and write: lane writes q=w*16+l15, kv chunk fn*16+l4*4 ----
    {
      const int q = w * 16 + l15;
      const int sw = SWZ(q);
#pragma unroll
      for (int fn = 0; fn < 4; ++fn) {
        uint2 u;
        u.x = cvt_pk_bf16(p[fn][0], p[fn][1]);
        u.y = cvt_pk_bf16(p[fn][2], p[fn][3]);
        *(uint2*)(Ps + q * 64 + ((fn * 16 + l4 * 4) ^ sw)) = u;
      }
    }
    asm volatile("s_waitcnt lgkmcnt(0)" ::: "memory");
    __builtin_amdgcn_sched_barrier(0);

    // ---- O += P V ----
    {
      const int q = w * 16 + l15;
      const int swp = SWZ(q);
      short8 pa0 = *(const short8*)(Ps + q * 64 + ((8 * l4) ^ swp));
      short8 pa1 = *(const short8*)(Ps + q * 64 + ((32 + 8 * l4) ^ swp));
#pragma unroll
      for (int fd = 0; fd < 4; ++fd) {
        const int dr = fd * 16 + l15;
        const int sw = SWZ(dr);
        short8 vb0 = *(const short8*)(Vt[cur] + dr * 64 + ((8 * l4) ^ sw));
        short8 vb1 = *(const short8*)(Vt[cur] + dr * 64 + ((32 + 8 * l4) ^ sw));
        of[fd] = __builtin_amdgcn_mfma_f32_16x16x32_bf16(pa0, vb0, of[fd], 0, 0, 0);
        of[fd] = __builtin_amdgcn_mfma_f32_16x16x32_bf16(pa1, vb1, of[fd], 0, 0, 0);
      }
    }

    // ---- land next V tile (compiler inserts vmcnt wait on pv regs) ----
    if (pf) {
#pragma unroll
      for (int j = 0; j < 8; ++j) {
        const int d = vd0 + j;
        const uint val = (uint)(ushort)pv0[j] | ((uint)(ushort)pv1[j] << 16);
        *(uint*)(Vt[cur ^ 1] + d * 64 + (vkv ^ SWZ(d))) = val;
      }
    }
    __syncthreads();  // implicit vmcnt(0)+lgkmcnt(0) drain covers K(t+1) visibility
    cur ^= 1;
  }

  // ---- epilogue: store UNNORMALIZED partial O and per-row m,l (log2 domain) ----
#pragma unroll
  for (int r = 0; r < 4; ++r) {
    const int qrow = q0 + w * 16 + l4 * 4 + r;
#pragma unroll
    for (int fd = 0; fd < 4; ++fd)
      Opart[(size_t)split * (NQ * DMODEL) + (size_t)qrow * DMODEL + h * HD + fd * 16 + l15] =
          of[fd][r];
  }
  if (l4 == 0) {
    const int qrow = q0 + w * 16 + l15;
    Mpart[(split * NH + h) * NQ + qrow] = m_run;
    Lpart[(split * NH + h) * NQ + qrow] = l_run;
  }
}

// ---------------- merge the 2 KV-split partials (m,l in log2 domain) ----------------
__global__ __launch_bounds__(256) void merge_kernel(
    const float* __restrict__ Opart, const float* __restrict__ Mpart,
    const float* __restrict__ Lpart, float* __restrict__ out) {
  const int i4 = blockIdx.x * 256 + threadIdx.x;  // group of 4 floats
  const int i = i4 * 4;
  const int q = i >> 9;        // / DMODEL
  const int col = i & 511;
  const int h = col >> 6;
  const float m0 = Mpart[h * NQ + q];
  const float m1 = Mpart[NH * NQ + h * NQ + q];
  const float mm = fmaxf(m0, m1);
  const float w0 = fast_exp2(m0 - mm);
  const float w1 = fast_exp2(m1 - mm);
  const float l = w0 * Lpart[h * NQ + q] + w1 * Lpart[NH * NQ + h * NQ + q];
  const float inv = 1.0f / l;
  const float4 o0 = ((const float4*)Opart)[i4];
  const float4 o1 = ((const float4*)(Opart + (size_t)NQ * DMODEL))[i4];
  float4 o;
  o.x = (w0 * o0.x + w1 * o1.x) * inv;
  o.y = (w0 * o0.y + w1 * o1.y) * inv;
  o.z = (w0 * o0.z + w1 * o1.z) * inv;
  o.w = (w0 * o0.w + w1 * o1.w) * inv;
  ((float4*)out)[i4] = o;
}

extern "C" void kernel_launch(void* const* d_in, const int* in_sizes, int n_in,
                              void* d_out, int out_size, void* d_ws, size_t ws_size,
                              hipStream_t stream) {
  const float* qin = (const float*)d_in[0];
  const float* kin = (const float*)d_in[1];
  const float* vin = (const float*)d_in[2];
  const float* Wq = (const float*)d_in[3];
  const float* Wk = (const float*)d_in[4];
  const float* Wv = (const float*)d_in[5];
  float* out = (float*)d_out;

  char* ws = (char*)d_ws;
  size_t off = 0;
  ushort* qb = (ushort*)(ws + off); off += (size_t)NQ * DIN * 2;
  ushort* kb = (ushort*)(ws + off); off += (size_t)NKV * DIN * 2;
  ushort* vb = (ushort*)(ws + off); off += (size_t)NKV * DIN * 2;
  ushort* wqb = (ushort*)(ws + off); off += (size_t)DMODEL * DIN * 2;
  ushort* wkb = (ushort*)(ws + off); off += (size_t)DMODEL * DIN * 2;
  ushort* wvb = (ushort*)(ws + off); off += (size_t)DMODEL * DIN * 2;
  ushort* Qp = (ushort*)(ws + off); off += (size_t)NQ * DMODEL * 2;
  ushort* Kp = (ushort*)(ws + off); off += (size_t)NKV * DMODEL * 2;
  ushort* Vp = (ushort*)(ws + off); off += (size_t)NKV * DMODEL * 2;
  float* Opart = (float*)(ws + off); off += (size_t)NSPLIT * NQ * DMODEL * 4;
  float* Mpart = (float*)(ws + off); off += (size_t)NSPLIT * NH * NQ * 4;
  float* Lpart = (float*)(ws + off); off += (size_t)NSPLIT * NH * NQ * 4;

  // cast inputs (3 x 4096x1024, n4 = 2^20) and weights (3 x 512x1024, n4 = 2^17)
  cast3_kernel<<<2048, 256, 0, stream>>>(qin, kin, vin, qb, kb, vb, 20);
  cast3_kernel<<<1536, 256, 0, stream>>>(Wq, Wk, Wv, wqb, wkb, wvb, 17);
  // projections: Qp/Kp/Vp [4096][512] bf16
  proj_gemm<<<dim3(64, 4, 3), 256, 0, stream>>>(qb, wqb, Qp, kb, wkb, Kp, vb, wvb, Vp);
  // fused attention, KV-split x2
  attn_kernel<<<dim3(64, NH, NSPLIT), 256, 0, stream>>>(Qp, Kp, Vp, Opart, Mpart, Lpart);
  // merge partials
  merge_kernel<<<(NQ * DMODEL / 4) / 256, 256, 0, stream>>>(Opart, Mpart, Lpart, out);
}

// Round 5
// 198.131 us; speedup vs baseline: 1.3334x; 1.1425x over previous
//
#include <hip/hip_runtime.h>
#include <hip/hip_bf16.h>

#define NQ 4096
#define NKV 4096
#define DIN 1024
#define NH 8
#define HD 64
#define DMODEL 512
#define NSPLIT 4
#define KVQ (NKV / NSPLIT)
#define QBLK 128

typedef __attribute__((ext_vector_type(4))) float f32x4;
typedef __attribute__((ext_vector_type(8))) short short8;

#define GPTR(p) ((const __attribute__((address_space(1))) void*)(p))
#define SPTR(p) ((__attribute__((address_space(3))) void*)(p))
// XOR swizzle (in 8-element groups) to spread 128B-row LDS tiles across banks
#define SWZ(r) ((((r) ^ ((r) >> 3)) & 7) << 3)

// 0.125 (1/sqrt(64)) * log2(e): softmax computed in exp2 domain
#define SM_SCALE 0.1803368801111204f

__device__ __forceinline__ ushort f2b(float f) {
  uint u = __float_as_uint(f);
  u = (u + 0x7fffu + ((u >> 16) & 1u)) >> 16;
  return (ushort)u;
}

__device__ __forceinline__ uint cvt_pk_bf16(float lo, float hi) {
  uint r;
  asm("v_cvt_pk_bf16_f32 %0, %1, %2" : "=v"(r) : "v"(lo), "v"(hi));
  return r;
}

__device__ __forceinline__ float fast_exp2(float x) {
  float r;
  asm("v_exp_f32 %0, %1" : "=v"(r) : "v"(x));
  return r;
}

// Reduce over lane group {l15, l15+16, l15+32, l15+48} via VALU permlane swaps.
// v_permlane*_swap modifies BOTH operands -> they MUST be distinct registers:
// early-clobber outputs + in-asm v_mov materialization prevents the register
// allocator from coalescing the two copies of x into one VGPR (R4 bug).
__device__ __forceinline__ float red_max4(float x) {
  float a, b;
  asm("v_mov_b32 %0, %2\n\t"
      "v_mov_b32 %1, %2\n\t"
      "v_permlane32_swap_b32 %0, %1"
      : "=&v"(a), "=&v"(b)
      : "v"(x));
  const float m1 = fmaxf(a, b);  // period-32 replicated pairwise max
  float c, d;
  asm("v_mov_b32 %0, %2\n\t"
      "v_mov_b32 %1, %2\n\t"
      "v_permlane16_swap_b32 %0, %1"
      : "=&v"(c), "=&v"(d)
      : "v"(m1));
  return fmaxf(c, d);  // full 4-group max, replicated in all lanes
}

__device__ __forceinline__ float red_sum4(float x) {
  float a, b;
  asm("v_mov_b32 %0, %2\n\t"
      "v_mov_b32 %1, %2\n\t"
      "v_permlane32_swap_b32 %0, %1"
      : "=&v"(a), "=&v"(b)
      : "v"(x));
  const float s = a + b;
  float c, d;
  asm("v_mov_b32 %0, %2\n\t"
      "v_mov_b32 %1, %2\n\t"
      "v_permlane16_swap_b32 %0, %1"
      : "=&v"(c), "=&v"(d)
      : "v"(s));
  return c + d;
}

// ---------------- cast: 3 equal-size f32 arrays -> bf16 ----------------
__global__ void cast3_kernel(const float* __restrict__ s0, const float* __restrict__ s1,
                             const float* __restrict__ s2, ushort* __restrict__ d0,
                             ushort* __restrict__ d1, ushort* __restrict__ d2, int shift) {
  const int n4 = 1 << shift;
  const int total = 3 * n4;
  for (int u = blockIdx.x * blockDim.x + threadIdx.x; u < total;
       u += gridDim.x * blockDim.x) {
    const int a = u >> shift;
    const int off = u & (n4 - 1);
    const float4* src = (const float4*)(a == 0 ? s0 : a == 1 ? s1 : s2);
    ushort* dst = a == 0 ? d0 : a == 1 ? d1 : d2;
    float4 v = src[off];
    ushort4 o = make_ushort4(f2b(v.x), f2b(v.y), f2b(v.z), f2b(v.w));
    ((ushort4*)dst)[off] = o;
  }
}

// ---------------- projection GEMM: C[4096][512] = A[4096][1024] * W^T ----------------
__global__ __launch_bounds__(256) void proj_gemm(
    const ushort* __restrict__ A0, const ushort* __restrict__ B0, ushort* __restrict__ C0,
    const ushort* __restrict__ A1, const ushort* __restrict__ B1, ushort* __restrict__ C1,
    const ushort* __restrict__ A2, const ushort* __restrict__ B2, ushort* __restrict__ C2) {
  const int z = blockIdx.z;
  const ushort* A = z == 0 ? A0 : z == 1 ? A1 : A2;
  const ushort* B = z == 0 ? B0 : z == 1 ? B1 : B2;
  ushort* C = z == 0 ? C0 : z == 1 ? C1 : C2;

  __shared__ ushort As[64 * 32];
  __shared__ ushort Bs[128 * 32];
  const int tid = threadIdx.x;
  const int w = tid >> 6, lane = tid & 63;
  const int wr = w >> 1, wc = w & 1;
  const int bm = blockIdx.x, bn = blockIdx.y;
  const int l15 = lane & 15, l4 = lane >> 4;

  f32x4 acc[2][4];
#pragma unroll
  for (int m = 0; m < 2; ++m)
#pragma unroll
    for (int n = 0; n < 4; ++n) acc[m][n] = (f32x4){0.f, 0.f, 0.f, 0.f};

  const size_t abase = (size_t)(bm * 64) * DIN;
  const size_t bbase = (size_t)(bn * 128) * DIN;
  const int srow = lane >> 2;
  const int schunk = (lane & 3) * 8;
  const int fcol = l4 * 8;

  for (int k0 = 0; k0 < DIN; k0 += 32) {
    __builtin_amdgcn_global_load_lds(
        GPTR(A + abase + (size_t)(w * 16 + srow) * DIN + k0 + schunk),
        SPTR(As + w * 512), 16, 0, 0);
#pragma unroll
    for (int j = 0; j < 2; ++j) {
      const int slot = w * 2 + j;
      __builtin_amdgcn_global_load_lds(
          GPTR(B + bbase + (size_t)(slot * 16 + srow) * DIN + k0 + schunk),
          SPTR(Bs + slot * 512), 16, 0, 0);
    }
    __syncthreads();
    short8 af[2], bfr[4];
#pragma unroll
    for (int m = 0; m < 2; ++m)
      af[m] = *(const short8*)(As + (wr * 32 + m * 16 + l15) * 32 + fcol);
#pragma unroll
    for (int n = 0; n < 4; ++n)
      bfr[n] = *(const short8*)(Bs + (wc * 64 + n * 16 + l15) * 32 + fcol);
#pragma unroll
    for (int m = 0; m < 2; ++m)
#pragma unroll
      for (int n = 0; n < 4; ++n)
        acc[m][n] = __builtin_amdgcn_mfma_f32_16x16x32_bf16(af[m], bfr[n], acc[m][n], 0, 0, 0);
    __syncthreads();
  }

  const int orow = bm * 64 + wr * 32 + l4 * 4;
  const int ocol = bn * 128 + wc * 64 + l15;
#pragma unroll
  for (int m = 0; m < 2; ++m)
#pragma unroll
    for (int n = 0; n < 4; ++n)
#pragma unroll
      for (int r = 0; r < 4; ++r)
        C[(size_t)(orow + m * 16 + r) * DMODEL + ocol + n * 16] = f2b(acc[m][n][r]);
}

// ---------------- fused flash attention (KV-split x4, QBLK=128) ----------------
// 4 waves x 32 q-rows each; KVBLK=64; 16 iters/block. Swapped QK^T; in-register
// softmax with permlane reductions; single barrier/iter; K dbuf via global_load_lds.
__global__ __launch_bounds__(256, 3) void attn_kernel(
    const ushort* __restrict__ Qp, const ushort* __restrict__ Kp,
    const ushort* __restrict__ Vp, float* __restrict__ Opart,
    float* __restrict__ Mpart, float* __restrict__ Lpart) {
  __shared__ ushort Ks[2][64 * 64];
  __shared__ ushort Vt[2][64 * 64];  // transposed V: [d][kv]
  __shared__ ushort Ps[QBLK * 64];   // Q staging (prologue), then P (bf16) [q][kv]
  const int h = blockIdx.y;
  const int q0 = blockIdx.x * QBLK;
  const int split = blockIdx.z;
  const int kvbase = split * KVQ;
  const int tid = threadIdx.x;
  const int w = tid >> 6, lane = tid & 63;
  const int l15 = lane & 15, l4 = lane >> 4;

  // K staging geometry (64x64 tile, 2 gload/thread, pre-swizzled source)
  const int lrow = lane >> 3, lch = lane & 7;
  int srow[2], sch[2];
#pragma unroll
  for (int j = 0; j < 2; ++j) {
    const int row = (w * 2 + j) * 8 + lrow;
    srow[j] = row;
    sch[j] = (lch ^ ((row ^ (row >> 3)) & 7)) * 8;
  }
  // V staging geometry (conflict-free: kv from low tid bits)
  const int vkv = w * 16 + (lane & 7) * 2;
  const int vd0 = ((lane >> 3) & 7) * 8;

  // ---- prologue: stage Q (128 rows -> Ps), K(0), V(0) ----
#pragma unroll
  for (int j = 0; j < 4; ++j) {
    const int row = (w * 4 + j) * 8 + lrow;
    const int ch = (lch ^ ((row ^ (row >> 3)) & 7)) * 8;
    __builtin_amdgcn_global_load_lds(
        GPTR(Qp + (size_t)(q0 + row) * DMODEL + h * HD + ch),
        SPTR(Ps + (w * 4 + j) * 512), 16, 0, 0);
  }
#pragma unroll
  for (int j = 0; j < 2; ++j)
    __builtin_amdgcn_global_load_lds(
        GPTR(Kp + (size_t)(kvbase + srow[j]) * DMODEL + h * HD + sch[j]),
        SPTR(Ks[0] + (w * 2 + j) * 512), 16, 0, 0);
  short8 vr0 = *(const short8*)(Vp + (size_t)(kvbase + vkv) * DMODEL + h * HD + vd0);
  short8 vr1 = *(const short8*)(Vp + (size_t)(kvbase + vkv + 1) * DMODEL + h * HD + vd0);
  asm volatile("s_waitcnt vmcnt(0)" ::: "memory");
  // hoist Q fragments (wave-local rows w*32..w*32+31)
  short8 qa[2][2];
#pragma unroll
  for (int fq = 0; fq < 2; ++fq) {
    const int q = w * 32 + fq * 16 + l15;
    const int sw = SWZ(q);
    qa[fq][0] = *(const short8*)(Ps + q * 64 + ((8 * l4) ^ sw));
    qa[fq][1] = *(const short8*)(Ps + q * 64 + ((32 + 8 * l4) ^ sw));
  }
  // write V tile 0 transposed
#pragma unroll
  for (int j = 0; j < 8; ++j) {
    const int d = vd0 + j;
    const uint val = (uint)(ushort)vr0[j] | ((uint)(ushort)vr1[j] << 16);
    *(uint*)(Vt[0] + d * 64 + (vkv ^ SWZ(d))) = val;
  }
  __syncthreads();

  // per-lane softmax state: q-row = w*32 + fq*16 + l15 (replicated across l4)
  float m_run[2] = {-1e30f, -1e30f}, l_run[2] = {0.f, 0.f};
  f32x4 of[2][4];
#pragma unroll
  for (int fq = 0; fq < 2; ++fq)
#pragma unroll
    for (int fd = 0; fd < 4; ++fd) of[fq][fd] = (f32x4){0.f, 0.f, 0.f, 0.f};

  int cur = 0;
  for (int it = 0; it < KVQ / 64; ++it) {
    // ---- issue next tile's loads first ----
    short8 pv0, pv1;
    const bool pf = (it + 1) < KVQ / 64;
    if (pf) {
      const int kvn = kvbase + (it + 1) * 64;
#pragma unroll
      for (int j = 0; j < 2; ++j)
        __builtin_amdgcn_global_load_lds(
            GPTR(Kp + (size_t)(kvn + srow[j]) * DMODEL + h * HD + sch[j]),
            SPTR(Ks[cur ^ 1] + (w * 2 + j) * 512), 16, 0, 0);
      pv0 = *(const short8*)(Vp + (size_t)(kvn + vkv) * DMODEL + h * HD + vd0);
      pv1 = *(const short8*)(Vp + (size_t)(kvn + vkv + 1) * DMODEL + h * HD + vd0);
    }

    // ---- S^T = K Q^T : sf[fq][fn][r] = S[kv=fn*16+l4*4+r][q=w*32+fq*16+l15] ----
    f32x4 sf[2][4];
#pragma unroll
    for (int fq = 0; fq < 2; ++fq)
#pragma unroll
      for (int fn = 0; fn < 4; ++fn) sf[fq][fn] = (f32x4){0.f, 0.f, 0.f, 0.f};
#pragma unroll
    for (int fn = 0; fn < 4; ++fn) {
      const int kvr = fn * 16 + l15;
      const int sw = SWZ(kvr);
      short8 kb0 = *(const short8*)(Ks[cur] + kvr * 64 + ((8 * l4) ^ sw));
      short8 kb1 = *(const short8*)(Ks[cur] + kvr * 64 + ((32 + 8 * l4) ^ sw));
      sf[0][fn] = __builtin_amdgcn_mfma_f32_16x16x32_bf16(kb0, qa[0][0], sf[0][fn], 0, 0, 0);
      sf[0][fn] = __builtin_amdgcn_mfma_f32_16x16x32_bf16(kb1, qa[0][1], sf[0][fn], 0, 0, 0);
      sf[1][fn] = __builtin_amdgcn_mfma_f32_16x16x32_bf16(kb0, qa[1][0], sf[1][fn], 0, 0, 0);
      sf[1][fn] = __builtin_amdgcn_mfma_f32_16x16x32_bf16(kb1, qa[1][1], sf[1][fn], 0, 0, 0);
    }

    // ---- in-register online softmax (exp2 domain), per fq ----
#pragma unroll
    for (int fq = 0; fq < 2; ++fq) {
      float t0 = fmaxf(fmaxf(sf[fq][0][0], sf[fq][0][1]), fmaxf(sf[fq][0][2], sf[fq][0][3]));
      float t1 = fmaxf(fmaxf(sf[fq][1][0], sf[fq][1][1]), fmaxf(sf[fq][1][2], sf[fq][1][3]));
      float t2 = fmaxf(fmaxf(sf[fq][2][0], sf[fq][2][1]), fmaxf(sf[fq][2][2], sf[fq][2][3]));
      float t3 = fmaxf(fmaxf(sf[fq][3][0], sf[fq][3][1]), fmaxf(sf[fq][3][2], sf[fq][3][3]));
      float rmax2 = red_max4(fmaxf(fmaxf(t0, t1), fmaxf(t2, t3)) * SM_SCALE);
      // T13 defer-max: bounds p by 2^8
      if (__any(rmax2 > m_run[fq] + 8.0f)) {
        const float mnew = fmaxf(m_run[fq], rmax2);
        const float alpha = fast_exp2(m_run[fq] - mnew);
        m_run[fq] = mnew;
        l_run[fq] *= alpha;
        float ar[4];
#pragma unroll
        for (int r = 0; r < 4; ++r) ar[r] = __shfl(alpha, l4 * 4 + r);
#pragma unroll
        for (int fd = 0; fd < 4; ++fd)
#pragma unroll
          for (int r = 0; r < 4; ++r) of[fq][fd][r] *= ar[r];
      }
      float rsum = 0.f;
#pragma unroll
      for (int fn = 0; fn < 4; ++fn)
#pragma unroll
        for (int r = 0; r < 4; ++r) {
          const float v = fast_exp2(__builtin_fmaf(sf[fq][fn][r], SM_SCALE, -m_run[fq]));
          sf[fq][fn][r] = v;  // overlay P into sf storage
          rsum += v;
        }
      l_run[fq] += red_sum4(rsum);
    }

    // ---- pack P to bf16, write to Ps (wave-local rows) ----
#pragma unroll
    for (int fq = 0; fq < 2; ++fq) {
      const int q = w * 32 + fq * 16 + l15;
      const int sw = SWZ(q);
#pragma unroll
      for (int fn = 0; fn < 4; ++fn) {
        uint2 u;
        u.x = cvt_pk_bf16(sf[fq][fn][0], sf[fq][fn][1]);
        u.y = cvt_pk_bf16(sf[fq][fn][2], sf[fq][fn][3]);
        *(uint2*)(Ps + q * 64 + ((fn * 16 + l4 * 4) ^ sw)) = u;
      }
    }
    asm volatile("s_waitcnt lgkmcnt(0)" ::: "memory");
    __builtin_amdgcn_sched_barrier(0);

    // ---- O += P V ----
    {
      short8 pa[2][2];
#pragma unroll
      for (int fq = 0; fq < 2; ++fq) {
        const int q = w * 32 + fq * 16 + l15;
        const int swp = SWZ(q);
        pa[fq][0] = *(const short8*)(Ps + q * 64 + ((8 * l4) ^ swp));
        pa[fq][1] = *(const short8*)(Ps + q * 64 + ((32 + 8 * l4) ^ swp));
      }
#pragma unroll
      for (int fd = 0; fd < 4; ++fd) {
        const int dr = fd * 16 + l15;
        const int sw = SWZ(dr);
        short8 vb0 = *(const short8*)(Vt[cur] + dr * 64 + ((8 * l4) ^ sw));
        short8 vb1 = *(const short8*)(Vt[cur] + dr * 64 + ((32 + 8 * l4) ^ sw));
        of[0][fd] = __builtin_amdgcn_mfma_f32_16x16x32_bf16(pa[0][0], vb0, of[0][fd], 0, 0, 0);
        of[0][fd] = __builtin_amdgcn_mfma_f32_16x16x32_bf16(pa[0][1], vb1, of[0][fd], 0, 0, 0);
        of[1][fd] = __builtin_amdgcn_mfma_f32_16x16x32_bf16(pa[1][0], vb0, of[1][fd], 0, 0, 0);
        of[1][fd] = __builtin_amdgcn_mfma_f32_16x16x32_bf16(pa[1][1], vb1, of[1][fd], 0, 0, 0);
      }
    }

    // ---- land next V tile ----
    if (pf) {
#pragma unroll
      for (int j = 0; j < 8; ++j) {
        const int d = vd0 + j;
        const uint val = (uint)(ushort)pv0[j] | ((uint)(ushort)pv1[j] << 16);
        *(uint*)(Vt[cur ^ 1] + d * 64 + (vkv ^ SWZ(d))) = val;
      }
    }
    __syncthreads();
    cur ^= 1;
  }

  // ---- epilogue: store UNNORMALIZED partial O and per-row m,l (log2 domain) ----
#pragma unroll
  for (int fq = 0; fq < 2; ++fq) {
#pragma unroll
    for (int r = 0; r < 4; ++r) {
      const int qrow = q0 + w * 32 + fq * 16 + l4 * 4 + r;
#pragma unroll
      for (int fd = 0; fd < 4; ++fd)
        Opart[(size_t)split * (NQ * DMODEL) + (size_t)qrow * DMODEL + h * HD + fd * 16 + l15] =
            of[fq][fd][r];
    }
    if (l4 == 0) {
      const int qrow = q0 + w * 32 + fq * 16 + l15;
      Mpart[(split * NH + h) * NQ + qrow] = m_run[fq];
      Lpart[(split * NH + h) * NQ + qrow] = l_run[fq];
    }
  }
}

// ---------------- merge the 4 KV-split partials (m,l in log2 domain) ----------------
__global__ __launch_bounds__(256) void merge_kernel(
    const float* __restrict__ Opart, const float* __restrict__ Mpart,
    const float* __restrict__ Lpart, float* __restrict__ out) {
  const int i4 = blockIdx.x * 256 + threadIdx.x;
  const int i = i4 * 4;
  const int q = i >> 9;
  const int col = i & 511;
  const int h = col >> 6;
  float m[NSPLIT];
  float mm = -1e30f;
#pragma unroll
  for (int s = 0; s < NSPLIT; ++s) {
    m[s] = Mpart[(s * NH + h) * NQ + q];
    mm = fmaxf(mm, m[s]);
  }
  float l = 0.f, ws[NSPLIT];
#pragma unroll
  for (int s = 0; s < NSPLIT; ++s) {
    ws[s] = fast_exp2(m[s] - mm);
    l += ws[s] * Lpart[(s * NH + h) * NQ + q];
  }
  const float inv = 1.0f / l;
  float4 o = {0.f, 0.f, 0.f, 0.f};
#pragma unroll
  for (int s = 0; s < NSPLIT; ++s) {
    const float4 os = ((const float4*)(Opart + (size_t)s * NQ * DMODEL))[i4];
    o.x += ws[s] * os.x;
    o.y += ws[s] * os.y;
    o.z += ws[s] * os.z;
    o.w += ws[s] * os.w;
  }
  o.x *= inv; o.y *= inv; o.z *= inv; o.w *= inv;
  ((float4*)out)[i4] = o;
}

extern "C" void kernel_launch(void* const* d_in, const int* in_sizes, int n_in,
                              void* d_out, int out_size, void* d_ws, size_t ws_size,
                              hipStream_t stream) {
  const float* qin = (const float*)d_in[0];
  const float* kin = (const float*)d_in[1];
  const float* vin = (const float*)d_in[2];
  const float* Wq = (const float*)d_in[3];
  const float* Wk = (const float*)d_in[4];
  const float* Wv = (const float*)d_in[5];
  float* out = (float*)d_out;

  char* ws = (char*)d_ws;
  const size_t MB = 1 << 20;
  // Layout (45MB high-water). Opart (32MB) aliases qb/kb/vb/w, which are dead
  // by the time attn writes it (stream-ordered).
  ushort* Qp = (ushort*)(ws + 0 * MB);    // 4MB
  ushort* Kp = (ushort*)(ws + 4 * MB);    // 4MB
  ushort* Vp = (ushort*)(ws + 8 * MB);    // 4MB
  ushort* qb = (ushort*)(ws + 12 * MB);   // 8MB
  ushort* kb = (ushort*)(ws + 20 * MB);   // 8MB
  ushort* vb = (ushort*)(ws + 28 * MB);   // 8MB
  ushort* wqb = (ushort*)(ws + 36 * MB);  // 1MB
  ushort* wkb = (ushort*)(ws + 37 * MB);  // 1MB
  ushort* wvb = (ushort*)(ws + 38 * MB);  // 1MB
  float* Opart = (float*)(ws + 12 * MB);  // 32MB (alias)
  float* Mpart = (float*)(ws + 44 * MB);  // 512KB
  float* Lpart = (float*)(ws + 44 * MB + 512 * 1024);  // 512KB

  cast3_kernel<<<2048, 256, 0, stream>>>(qin, kin, vin, qb, kb, vb, 20);
  cast3_kernel<<<1536, 256, 0, stream>>>(Wq, Wk, Wv, wqb, wkb, wvb, 17);
  proj_gemm<<<dim3(64, 4, 3), 256, 0, stream>>>(qb, wqb, Qp, kb, wkb, Kp, vb, wvb, Vp);
  attn_kernel<<<dim3(NQ / QBLK, NH, NSPLIT), 256, 0, stream>>>(Qp, Kp, Vp, Opart, Mpart, Lpart);
  merge_kernel<<<(NQ * DMODEL / 4) / 256, 256, 0, stream>>>(Opart, Mpart, Lpart, out);
}

// Round 8
// 191.668 us; speedup vs baseline: 1.3783x; 1.0337x over previous
//
#include <hip/hip_runtime.h>
#include <hip/hip_bf16.h>

#define NQ 4096
#define NKV 4096
#define DIN 1024
#define NH 8
#define HD 64
#define DMODEL 512
#define NSPLIT 4
#define KVQ (NKV / NSPLIT)
#define QBLK 128
#define NT (KVQ / 64)

typedef __attribute__((ext_vector_type(4))) float f32x4;
typedef __attribute__((ext_vector_type(8))) short short8;

#define GPTR(p) ((const __attribute__((address_space(1))) void*)(p))
#define SPTR(p) ((__attribute__((address_space(3))) void*)(p))
// XOR swizzle (in 8-element groups) to spread 128B-row LDS tiles across banks
#define SWZ(r) ((((r) ^ ((r) >> 3)) & 7) << 3)

// 0.125 (1/sqrt(64)) * log2(e): softmax computed in exp2 domain
#define SM_SCALE 0.1803368801111204f

__device__ __forceinline__ ushort f2b(float f) {
  uint u = __float_as_uint(f);
  u = (u + 0x7fffu + ((u >> 16) & 1u)) >> 16;
  return (ushort)u;
}

__device__ __forceinline__ uint cvt_pk_bf16(float lo, float hi) {
  uint r;
  asm("v_cvt_pk_bf16_f32 %0, %1, %2" : "=v"(r) : "v"(lo), "v"(hi));
  return r;
}

__device__ __forceinline__ float fast_exp2(float x) {
  float r;
  asm("v_exp_f32 %0, %1" : "=v"(r) : "v"(x));
  return r;
}

// Reduce over lane group {l15, l15+16, l15+32, l15+48} via VALU permlane swaps.
// Same-value operands MUST be materialized into distinct regs (R4 lesson).
__device__ __forceinline__ float red_max4(float x) {
  float a, b;
  asm("v_mov_b32 %0, %2\n\t"
      "v_mov_b32 %1, %2\n\t"
      "v_permlane32_swap_b32 %0, %1"
      : "=&v"(a), "=&v"(b)
      : "v"(x));
  const float m1 = fmaxf(a, b);
  float c, d;
  asm("v_mov_b32 %0, %2\n\t"
      "v_mov_b32 %1, %2\n\t"
      "v_permlane16_swap_b32 %0, %1"
      : "=&v"(c), "=&v"(d)
      : "v"(m1));
  return fmaxf(c, d);
}

// Two-input swap pairs (distinct SSA values -> in-place "+v" is safe).
__device__ __forceinline__ void plane32_swap(uint& a, uint& b) {
  asm("v_permlane32_swap_b32 %0, %1" : "+v"(a), "+v"(b));
}
__device__ __forceinline__ void plane16_swap(uint& a, uint& b) {
  asm("v_permlane16_swap_b32 %0, %1" : "+v"(a), "+v"(b));
}

union U4S8 { uint4 u; short8 s; };

// ---------------- cast: 3 equal-size f32 arrays -> bf16 ----------------
__global__ void cast3_kernel(const float* __restrict__ s0, const float* __restrict__ s1,
                             const float* __restrict__ s2, ushort* __restrict__ d0,
                             ushort* __restrict__ d1, ushort* __restrict__ d2, int shift) {
  const int n4 = 1 << shift;
  const int total = 3 * n4;
  for (int u = blockIdx.x * blockDim.x + threadIdx.x; u < total;
       u += gridDim.x * blockDim.x) {
    const int a = u >> shift;
    const int off = u & (n4 - 1);
    const float4* src = (const float4*)(a == 0 ? s0 : a == 1 ? s1 : s2);
    ushort* dst = a == 0 ? d0 : a == 1 ? d1 : d2;
    float4 v = src[off];
    ushort4 o = make_ushort4(f2b(v.x), f2b(v.y), f2b(v.z), f2b(v.w));
    ((ushort4*)dst)[off] = o;
  }
}

// ---------------- projection GEMM: C[4096][512] = A[4096][1024] * W^T ----------------
// 64x128 tile, BK=64, double-buffered global_load_lds staging, ONE barrier per
// K-step, swizzled LDS. Grid (64,4,3)=768 = exactly 3 blocks/CU, fully resident.
__global__ __launch_bounds__(256) void proj_gemm(
    const ushort* __restrict__ A0, const ushort* __restrict__ B0, ushort* __restrict__ C0,
    const ushort* __restrict__ A1, const ushort* __restrict__ B1, ushort* __restrict__ C1,
    const ushort* __restrict__ A2, const ushort* __restrict__ B2, ushort* __restrict__ C2) {
  const int z = blockIdx.z;
  const ushort* A = z == 0 ? A0 : z == 1 ? A1 : A2;
  const ushort* B = z == 0 ? B0 : z == 1 ? B1 : B2;
  ushort* C = z == 0 ? C0 : z == 1 ? C1 : C2;

  __shared__ ushort As[2][64 * 64];
  __shared__ ushort Bs[2][128 * 64];
  const int tid = threadIdx.x;
  const int w = tid >> 6, lane = tid & 63;
  const int wr = w >> 1, wc = w & 1;
  const int bm = blockIdx.x, bn = blockIdx.y;
  const int l15 = lane & 15, l4 = lane >> 4;
  const int lrow = lane >> 3, lch = lane & 7;

  f32x4 acc[2][4];
#pragma unroll
  for (int m = 0; m < 2; ++m)
#pragma unroll
    for (int n = 0; n < 4; ++n) acc[m][n] = (f32x4){0.f, 0.f, 0.f, 0.f};

  const size_t abase = (size_t)(bm * 64) * DIN;
  const size_t bbase = (size_t)(bn * 128) * DIN;

  // staging geometry: 8-row slots, pre-swizzled source chunk (rule #21)
  int arow[2], ach[2];
#pragma unroll
  for (int j = 0; j < 2; ++j) {
    const int row = (w * 2 + j) * 8 + lrow;
    arow[j] = row;
    ach[j] = (lch ^ ((row ^ (row >> 3)) & 7)) * 8;
  }
  int brow[4], bch[4];
#pragma unroll
  for (int j = 0; j < 4; ++j) {
    const int row = (w * 4 + j) * 8 + lrow;
    brow[j] = row;
    bch[j] = (lch ^ ((row ^ (row >> 3)) & 7)) * 8;
  }

  // prologue: stage k-tile 0 into buffer 0
#pragma unroll
  for (int j = 0; j < 2; ++j)
    __builtin_amdgcn_global_load_lds(GPTR(A + abase + (size_t)arow[j] * DIN + ach[j]),
                                     SPTR(As[0] + (w * 2 + j) * 512), 16, 0, 0);
#pragma unroll
  for (int j = 0; j < 4; ++j)
    __builtin_amdgcn_global_load_lds(GPTR(B + bbase + (size_t)brow[j] * DIN + bch[j]),
                                     SPTR(Bs[0] + (w * 4 + j) * 512), 16, 0, 0);
  __syncthreads();

  int cur = 0;
  for (int it = 0; it < DIN / 64; ++it) {
    if (it + 1 < DIN / 64) {
      const int k0 = (it + 1) * 64;
#pragma unroll
      for (int j = 0; j < 2; ++j)
        __builtin_amdgcn_global_load_lds(
            GPTR(A + abase + (size_t)arow[j] * DIN + k0 + ach[j]),
            SPTR(As[cur ^ 1] + (w * 2 + j) * 512), 16, 0, 0);
#pragma unroll
      for (int j = 0; j < 4; ++j)
        __builtin_amdgcn_global_load_lds(
            GPTR(B + bbase + (size_t)brow[j] * DIN + k0 + bch[j]),
            SPTR(Bs[cur ^ 1] + (w * 4 + j) * 512), 16, 0, 0);
    }
    short8 af[2][2], bfr[4][2];
#pragma unroll
    for (int m = 0; m < 2; ++m) {
      const int row = wr * 32 + m * 16 + l15;
      const int sw = SWZ(row);
      af[m][0] = *(const short8*)(As[cur] + row * 64 + ((8 * l4) ^ sw));
      af[m][1] = *(const short8*)(As[cur] + row * 64 + ((32 + 8 * l4) ^ sw));
    }
#pragma unroll
    for (int n = 0; n < 4; ++n) {
      const int row = wc * 64 + n * 16 + l15;
      const int sw = SWZ(row);
      bfr[n][0] = *(const short8*)(Bs[cur] + row * 64 + ((8 * l4) ^ sw));
      bfr[n][1] = *(const short8*)(Bs[cur] + row * 64 + ((32 + 8 * l4) ^ sw));
    }
#pragma unroll
    for (int ks = 0; ks < 2; ++ks)
#pragma unroll
      for (int m = 0; m < 2; ++m)
#pragma unroll
        for (int n = 0; n < 4; ++n)
          acc[m][n] =
              __builtin_amdgcn_mfma_f32_16x16x32_bf16(af[m][ks], bfr[n][ks], acc[m][n], 0, 0, 0);
    __syncthreads();
    cur ^= 1;
  }

  const int orow = bm * 64 + wr * 32 + l4 * 4;
  const int ocol = bn * 128 + wc * 64 + l15;
#pragma unroll
  for (int m = 0; m < 2; ++m)
#pragma unroll
    for (int n = 0; n < 4; ++n)
#pragma unroll
      for (int r = 0; r < 4; ++r)
        C[(size_t)(orow + m * 16 + r) * DMODEL + ocol + n * 16] = f2b(acc[m][n][r]);
}

// ---------------- fused flash attention (KV-split x4, QBLK=128) ----------------
// Swapped QK^T AND swapped PV: O^T[d][q]. P never touches LDS — redistributed
// kv-major -> B-fragment layout via cvt_pk + permlane16/32_swap. Row-sum l via
// MFMA against a register ones-fragment. LDS = Ks[2]+Vt[2] = 32KB -> 4 blocks/CU.
__global__ __launch_bounds__(256, 4) void attn_kernel(
    const ushort* __restrict__ Qp, const ushort* __restrict__ Kp,
    const ushort* __restrict__ Vp, float* __restrict__ Opart,
    float* __restrict__ Mpart, float* __restrict__ Lpart) {
  __shared__ ushort Ks[2][64 * 64];
  __shared__ ushort Vt[2][64 * 64];  // transposed V: [d][kv]
  const int h = blockIdx.y;
  const int q0 = blockIdx.x * QBLK;
  const int split = blockIdx.z;
  const int kvbase = split * KVQ;
  const int tid = threadIdx.x;
  const int w = tid >> 6, lane = tid & 63;
  const int l15 = lane & 15, l4 = lane >> 4;
  const int lrow = lane >> 3, lch = lane & 7;

  // K staging geometry (pre-swizzled source)
  int srow[2], sch[2];
#pragma unroll
  for (int j = 0; j < 2; ++j) {
    const int row = (w * 2 + j) * 8 + lrow;
    srow[j] = row;
    sch[j] = (lch ^ ((row ^ (row >> 3)) & 7)) * 8;
  }
  // V staging geometry (conflict-free: kv from low tid bits)
  const int vkv = w * 16 + (lane & 7) * 2;
  const int vd0 = ((lane >> 3) & 7) * 8;

  // ---- prologue ----
  // issue V(0) global loads early
  short8 vr0 = *(const short8*)(Vp + (size_t)(kvbase + vkv) * DMODEL + h * HD + vd0);
  short8 vr1 = *(const short8*)(Vp + (size_t)(kvbase + vkv + 1) * DMODEL + h * HD + vd0);
  // stage Q (128 rows) into Ks[0..1] region (16KB), wave-local rows w*32..w*32+31
  ushort* Qstage = &Ks[0][0];
#pragma unroll
  for (int j = 0; j < 4; ++j) {
    const int row = (w * 4 + j) * 8 + lrow;
    const int ch = (lch ^ ((row ^ (row >> 3)) & 7)) * 8;
    __builtin_amdgcn_global_load_lds(
        GPTR(Qp + (size_t)(q0 + row) * DMODEL + h * HD + ch),
        SPTR(Qstage + (w * 4 + j) * 512), 16, 0, 0);
  }
  asm volatile("s_waitcnt vmcnt(0)" ::: "memory");
  // hoist Q fragments (wave staged its own rows)
  short8 qa[2][2];
#pragma unroll
  for (int fq = 0; fq < 2; ++fq) {
    const int q = w * 32 + fq * 16 + l15;
    const int sw = SWZ(q);
    qa[fq][0] = *(const short8*)(Qstage + q * 64 + ((8 * l4) ^ sw));
    qa[fq][1] = *(const short8*)(Qstage + q * 64 + ((32 + 8 * l4) ^ sw));
  }
  __syncthreads();  // everyone done reading Q region before K(0)/V(0) land there
  // stage K(0)
#pragma unroll
  for (int j = 0; j < 2; ++j)
    __builtin_amdgcn_global_load_lds(
        GPTR(Kp + (size_t)(kvbase + srow[j]) * DMODEL + h * HD + sch[j]),
        SPTR(Ks[0] + (w * 2 + j) * 512), 16, 0, 0);
  // write V(0) transposed
#pragma unroll
  for (int j = 0; j < 8; ++j) {
    const int d = vd0 + j;
    const uint val = (uint)(ushort)vr0[j] | ((uint)(ushort)vr1[j] << 16);
    *(uint*)(Vt[0] + d * 64 + (vkv ^ SWZ(d))) = val;
  }
  __syncthreads();

  // ones A-fragment for MFMA row-sum (A row 0 = ones, rows 1-15 = 0)
  short8 ones;
  {
    const short ov = (l15 == 0) ? (short)0x3F80 : (short)0;
#pragma unroll
    for (int j = 0; j < 8; ++j) ones[j] = ov;
  }

  // per-lane softmax state for q = l15 (replicated across the 4 l4-groups)
  float m_run[2] = {-1e30f, -1e30f};
  f32x4 of[2][4];   // O^T frags: row d = fd*16+l4*4+r, col q = l15
  f32x4 of_l[2];    // l-sum frag: row0 (l4==0,r==0) holds sum
#pragma unroll
  for (int fq = 0; fq < 2; ++fq) {
    of_l[fq] = (f32x4){0.f, 0.f, 0.f, 0.f};
#pragma unroll
    for (int fd = 0; fd < 4; ++fd) of[fq][fd] = (f32x4){0.f, 0.f, 0.f, 0.f};
  }

  int cur = 0;
  for (int it = 0; it < NT; ++it) {
    // ---- issue next tile's loads first ----
    short8 pv0, pv1;
    const bool pf = (it + 1) < NT;
    if (pf) {
      const int kvn = kvbase + (it + 1) * 64;
#pragma unroll
      for (int j = 0; j < 2; ++j)
        __builtin_amdgcn_global_load_lds(
            GPTR(Kp + (size_t)(kvn + srow[j]) * DMODEL + h * HD + sch[j]),
            SPTR(Ks[cur ^ 1] + (w * 2 + j) * 512), 16, 0, 0);
      pv0 = *(const short8*)(Vp + (size_t)(kvn + vkv) * DMODEL + h * HD + vd0);
      pv1 = *(const short8*)(Vp + (size_t)(kvn + vkv + 1) * DMODEL + h * HD + vd0);
    }

    // ---- S^T = K Q^T : sf[fq][fn][r] = S[kv=fn*16+l4*4+r][q=w*32+fq*16+l15] ----
    f32x4 sf[2][4];
#pragma unroll
    for (int fq = 0; fq < 2; ++fq)
#pragma unroll
      for (int fn = 0; fn < 4; ++fn) sf[fq][fn] = (f32x4){0.f, 0.f, 0.f, 0.f};
#pragma unroll
    for (int fn = 0; fn < 4; ++fn) {
      const int kvr = fn * 16 + l15;
      const int sw = SWZ(kvr);
      short8 kb0 = *(const short8*)(Ks[cur] + kvr * 64 + ((8 * l4) ^ sw));
      short8 kb1 = *(const short8*)(Ks[cur] + kvr * 64 + ((32 + 8 * l4) ^ sw));
      sf[0][fn] = __builtin_amdgcn_mfma_f32_16x16x32_bf16(kb0, qa[0][0], sf[0][fn], 0, 0, 0);
      sf[0][fn] = __builtin_amdgcn_mfma_f32_16x16x32_bf16(kb1, qa[0][1], sf[0][fn], 0, 0, 0);
      sf[1][fn] = __builtin_amdgcn_mfma_f32_16x16x32_bf16(kb0, qa[1][0], sf[1][fn], 0, 0, 0);
      sf[1][fn] = __builtin_amdgcn_mfma_f32_16x16x32_bf16(kb1, qa[1][1], sf[1][fn], 0, 0, 0);
    }

    // ---- softmax + P redistribution (no LDS) ----
    short8 pb[2][2];  // [fq][ks] B-frags: P[kv=ks*32+l4*8+j][q=l15]
#pragma unroll
    for (int fq = 0; fq < 2; ++fq) {
      float t0 = fmaxf(fmaxf(sf[fq][0][0], sf[fq][0][1]), fmaxf(sf[fq][0][2], sf[fq][0][3]));
      float t1 = fmaxf(fmaxf(sf[fq][1][0], sf[fq][1][1]), fmaxf(sf[fq][1][2], sf[fq][1][3]));
      float t2 = fmaxf(fmaxf(sf[fq][2][0], sf[fq][2][1]), fmaxf(sf[fq][2][2], sf[fq][2][3]));
      float t3 = fmaxf(fmaxf(sf[fq][3][0], sf[fq][3][1]), fmaxf(sf[fq][3][2], sf[fq][3][3]));
      const float rmax2 = red_max4(fmaxf(fmaxf(t0, t1), fmaxf(t2, t3)) * SM_SCALE);
      // T13 defer-max: bounds p by 2^8; alpha is per-lane (q = l15)
      if (__any(rmax2 > m_run[fq] + 8.0f)) {
        const float mnew = fmaxf(m_run[fq], rmax2);
        const float alpha = fast_exp2(m_run[fq] - mnew);
        m_run[fq] = mnew;
#pragma unroll
        for (int fd = 0; fd < 4; ++fd)
#pragma unroll
          for (int r = 0; r < 4; ++r) of[fq][fd][r] *= alpha;
#pragma unroll
        for (int r = 0; r < 4; ++r) of_l[fq][r] *= alpha;
      }
#pragma unroll
      for (int fn = 0; fn < 4; ++fn)
#pragma unroll
        for (int r = 0; r < 4; ++r)
          sf[fq][fn][r] = fast_exp2(__builtin_fmaf(sf[fq][fn][r], SM_SCALE, -m_run[fq]));
      // pack to bf16 pairs: u[fn][c] = kv pair {fn*16+l4*4+2c, +1}
      uint u00 = cvt_pk_bf16(sf[fq][0][0], sf[fq][0][1]);
      uint u01 = cvt_pk_bf16(sf[fq][0][2], sf[fq][0][3]);
      uint u10 = cvt_pk_bf16(sf[fq][1][0], sf[fq][1][1]);
      uint u11 = cvt_pk_bf16(sf[fq][1][2], sf[fq][1][3]);
      uint u20 = cvt_pk_bf16(sf[fq][2][0], sf[fq][2][1]);
      uint u21 = cvt_pk_bf16(sf[fq][2][2], sf[fq][2][3]);
      uint u30 = cvt_pk_bf16(sf[fq][3][0], sf[fq][3][1]);
      uint u31 = cvt_pk_bf16(sf[fq][3][2], sf[fq][3][3]);
      // ks=0 (kv 0..31): plane32(u0,u1) then plane16 -> words
      {
        uint a = u00, b = u10;
        plane32_swap(a, b); plane16_swap(a, b);
        uint a1 = u01, b1 = u11;
        plane32_swap(a1, b1); plane16_swap(a1, b1);
        U4S8 t; t.u = make_uint4(a, a1, b, b1);
        pb[fq][0] = t.s;
      }
      // ks=1 (kv 32..63)
      {
        uint a = u20, b = u30;
        plane32_swap(a, b); plane16_swap(a, b);
        uint a1 = u21, b1 = u31;
        plane32_swap(a1, b1); plane16_swap(a1, b1);
        U4S8 t; t.u = make_uint4(a, a1, b, b1);
        pb[fq][1] = t.s;
      }
    }

    // ---- O^T += V^T P (A = V^T d-frags, B = P col-frags) ----
#pragma unroll
    for (int fd = 0; fd < 4; ++fd) {
      const int dr = fd * 16 + l15;
      const int sw = SWZ(dr);
      short8 vb0 = *(const short8*)(Vt[cur] + dr * 64 + ((8 * l4) ^ sw));
      short8 vb1 = *(const short8*)(Vt[cur] + dr * 64 + ((32 + 8 * l4) ^ sw));
      of[0][fd] = __builtin_amdgcn_mfma_f32_16x16x32_bf16(vb0, pb[0][0], of[0][fd], 0, 0, 0);
      of[0][fd] = __builtin_amdgcn_mfma_f32_16x16x32_bf16(vb1, pb[0][1], of[0][fd], 0, 0, 0);
      of[1][fd] = __builtin_amdgcn_mfma_f32_16x16x32_bf16(vb0, pb[1][0], of[1][fd], 0, 0, 0);
      of[1][fd] = __builtin_amdgcn_mfma_f32_16x16x32_bf16(vb1, pb[1][1], of[1][fd], 0, 0, 0);
    }
    // l-sum via ones-fragment MFMA
    of_l[0] = __builtin_amdgcn_mfma_f32_16x16x32_bf16(ones, pb[0][0], of_l[0], 0, 0, 0);
    of_l[0] = __builtin_amdgcn_mfma_f32_16x16x32_bf16(ones, pb[0][1], of_l[0], 0, 0, 0);
    of_l[1] = __builtin_amdgcn_mfma_f32_16x16x32_bf16(ones, pb[1][0], of_l[1], 0, 0, 0);
    of_l[1] = __builtin_amdgcn_mfma_f32_16x16x32_bf16(ones, pb[1][1], of_l[1], 0, 0, 0);

    // ---- land next V tile ----
    if (pf) {
#pragma unroll
      for (int j = 0; j < 8; ++j) {
        const int d = vd0 + j;
        const uint val = (uint)(ushort)pv0[j] | ((uint)(ushort)pv1[j] << 16);
        *(uint*)(Vt[cur ^ 1] + d * 64 + (vkv ^ SWZ(d))) = val;
      }
    }
    __syncthreads();
    cur ^= 1;
  }

  // ---- epilogue: vectorized partial-O stores + m,l ----
#pragma unroll
  for (int fq = 0; fq < 2; ++fq) {
    const int q = q0 + w * 32 + fq * 16 + l15;
    float* orow = Opart + (size_t)split * (NQ * DMODEL) + (size_t)q * DMODEL + h * HD;
#pragma unroll
    for (int fd = 0; fd < 4; ++fd)
      *(float4*)(orow + fd * 16 + l4 * 4) = *(float4*)&of[fq][fd];
    if (l4 == 0) {
      Mpart[(split * NH + h) * NQ + q] = m_run[fq];
      Lpart[(split * NH + h) * NQ + q] = of_l[fq][0];
    }
  }
}

// ---------------- merge the 4 KV-split partials (m in log2 domain) ----------------
__global__ __launch_bounds__(256) void merge_kernel(
    const float* __restrict__ Opart, const float* __restrict__ Mpart,
    const float* __restrict__ Lpart, float* __restrict__ out) {
  const int i4 = blockIdx.x * 256 + threadIdx.x;
  const int i = i4 * 4;
  const int q = i >> 9;
  const int col = i & 511;
  const int h = col >> 6;
  float m[NSPLIT];
  float mm = -1e30f;
#pragma unroll
  for (int s = 0; s < NSPLIT; ++s) {
    m[s] = Mpart[(s * NH + h) * NQ + q];
    mm = fmaxf(mm, m[s]);
  }
  float l = 0.f, ws[NSPLIT];
#pragma unroll
  for (int s = 0; s < NSPLIT; ++s) {
    ws[s] = fast_exp2(m[s] - mm);
    l += ws[s] * Lpart[(s * NH + h) * NQ + q];
  }
  const float inv = 1.0f / l;
  float4 o = {0.f, 0.f, 0.f, 0.f};
#pragma unroll
  for (int s = 0; s < NSPLIT; ++s) {
    const float4 os = ((const float4*)(Opart + (size_t)s * NQ * DMODEL))[i4];
    o.x += ws[s] * os.x;
    o.y += ws[s] * os.y;
    o.z += ws[s] * os.z;
    o.w += ws[s] * os.w;
  }
  o.x *= inv; o.y *= inv; o.z *= inv; o.w *= inv;
  ((float4*)out)[i4] = o;
}

extern "C" void kernel_launch(void* const* d_in, const int* in_sizes, int n_in,
                              void* d_out, int out_size, void* d_ws, size_t ws_size,
                              hipStream_t stream) {
  const float* qin = (const float*)d_in[0];
  const float* kin = (const float*)d_in[1];
  const float* vin = (const float*)d_in[2];
  const float* Wq = (const float*)d_in[3];
  const float* Wk = (const float*)d_in[4];
  const float* Wv = (const float*)d_in[5];
  float* out = (float*)d_out;

  char* ws = (char*)d_ws;
  const size_t MB = 1 << 20;
  // Layout (45MB high-water). Opart (32MB) aliases qb/kb/vb/w*, dead by then.
  ushort* Qp = (ushort*)(ws + 0 * MB);    // 4MB
  ushort* Kp = (ushort*)(ws + 4 * MB);    // 4MB
  ushort* Vp = (ushort*)(ws + 8 * MB);    // 4MB
  ushort* qb = (ushort*)(ws + 12 * MB);   // 8MB
  ushort* kb = (ushort*)(ws + 20 * MB);   // 8MB
  ushort* vb = (ushort*)(ws + 28 * MB);   // 8MB
  ushort* wqb = (ushort*)(ws + 36 * MB);  // 1MB
  ushort* wkb = (ushort*)(ws + 37 * MB);  // 1MB
  ushort* wvb = (ushort*)(ws + 38 * MB);  // 1MB
  float* Opart = (float*)(ws + 12 * MB);  // 32MB (alias)
  float* Mpart = (float*)(ws + 44 * MB);  // 512KB
  float* Lpart = (float*)(ws + 44 * MB + 512 * 1024);  // 512KB

  cast3_kernel<<<2048, 256, 0, stream>>>(qin, kin, vin, qb, kb, vb, 20);
  cast3_kernel<<<1536, 256, 0, stream>>>(Wq, Wk, Wv, wqb, wkb, wvb, 17);
  proj_gemm<<<dim3(64, 4, 3), 256, 0, stream>>>(qb, wqb, Qp, kb, wkb, Kp, vb, wvb, Vp);
  attn_kernel<<<dim3(NQ / QBLK, NH, NSPLIT), 256, 0, stream>>>(Qp, Kp, Vp, Opart, Mpart, Lpart);
  merge_kernel<<<(NQ * DMODEL / 4) / 256, 256, 0, stream>>>(Opart, Mpart, Lpart, out);
}